// Round 3
// baseline (120.581 us; speedup 1.0000x reference)
//
#include <hip/hip_runtime.h>
#include <cstdint>

#define NN 50000
#define NE 600000
#define D 128
#define BS 48               // slots per node; P(deg>=48|Poisson(12)) ~ 6e-14
#define NB2 1563            // fine buckets (dst>>5), 32 nodes each
#define PCAP2 640           // pairs per bucket: mean 384, sigma 19.6 -> 13-sigma margin
#define FA 147              // pass-A blocks: ceil(NE/4096)
#define WB1 16              // W1-pack blocks: 16384/1024
#define XB4 782             // x-convert blocks: ceil(800000/1024)

typedef __attribute__((ext_vector_type(8))) short short8;
typedef __attribute__((ext_vector_type(4))) float f32x4;

static __device__ __forceinline__ unsigned short f2bf(float f) {
  unsigned int u = __float_as_uint(f);
  unsigned int r = (u + 0x7FFFu + ((u >> 16) & 1u)) >> 16;   // RNE
  return (unsigned short)r;
}

// ------------------------------------------------ k_prep: fine edge binning + W1 pack + C/KB + x->bf16
//  [0,FA)            : bin edges into 1563 fine buckets (32 dst nodes each)
//  [FA,FA+WB1)       : pack W1 into MFMA B-fragment layout
//  [FA+WB1]          : C = W2@Wl (128x2), KB = b2@Wl + bl  (head collapse: gemm2 is linear)
//  [FA+WB1+1, ...)   : convert x -> bf16
__global__ __launch_bounds__(256) void k_prep(const float* __restrict__ x,
                                              const float* __restrict__ W1,
                                              const float* __restrict__ W2,
                                              const float* __restrict__ Wl,
                                              const float* __restrict__ b2,
                                              const float* __restrict__ bl,
                                              const int* __restrict__ ei,
                                              unsigned short* __restrict__ xb,
                                              unsigned short* __restrict__ W1p,
                                              float* __restrict__ Cf,
                                              float* __restrict__ KBf,
                                              int* __restrict__ gcnt,
                                              unsigned* __restrict__ pairs) {
  __shared__ int histA[NB2], baseA[NB2], curA[NB2];   // 18.3 KB
  int blk = blockIdx.x, t = threadIdx.x;
  if (blk < FA) {                                  // pass A: bin 4096 edges
    for (int i = t; i < NB2; i += 256) histA[i] = 0;
    __syncthreads();
    int e0 = blk * 4096 + t;
#pragma unroll
    for (int i = 0; i < 16; ++i) {
      int e = e0 + i * 256;
      if (e < NE) atomicAdd(&histA[ei[NE + e] >> 5], 1);
    }
    __syncthreads();
    for (int i = t; i < NB2; i += 256) {
      int h = histA[i];
      baseA[i] = h ? atomicAdd(&gcnt[i], h) : 0;
      curA[i] = 0;
    }
    __syncthreads();
#pragma unroll
    for (int i = 0; i < 16; ++i) {
      int e = e0 + i * 256;
      if (e < NE) {
        int s = ei[e];
        int d = ei[NE + e];
        int b = d >> 5;
        int p = baseA[b] + atomicAdd(&curA[b], 1);
        if (p < PCAP2) pairs[b * PCAP2 + p] = (unsigned)s | ((unsigned)(d & 31) << 16);
      }
    }
    return;
  }
  blk -= FA;
  if (blk < WB1) {                                 // pack W1: 4 items/thread
    int base = blk * 1024 + t;
#pragma unroll
    for (int i = 0; i < 4; ++i) {
      int rem = base + i * 256;                    // 0..16383
      int ks = rem >> 12;
      int nf = (rem >> 9) & 7;
      int l  = (rem >> 3) & 63;
      int j  = rem & 7;
      int k = ks * 32 + (l >> 4) * 8 + j;
      int n = nf * 16 + (l & 15);
      W1p[rem] = f2bf(W1[k * D + n]);
    }
    return;
  }
  blk -= WB1;
  if (blk == 0) {                                  // C = W2@Wl (fp32), KB = b2@Wl + bl
    {
      int k = t >> 1, c = t & 1;                   // 256 threads -> 128x2
      const float4* w2r = (const float4*)(W2 + k * D);
      float s = 0.f;
#pragma unroll
      for (int m4 = 0; m4 < 32; ++m4) {
        float4 wv = w2r[m4];
        int m = m4 * 4;
        s += wv.x * Wl[(m + 0) * 2 + c] + wv.y * Wl[(m + 1) * 2 + c] +
             wv.z * Wl[(m + 2) * 2 + c] + wv.w * Wl[(m + 3) * 2 + c];
      }
      Cf[k * 2 + c] = s;
    }
    if (t < 2) {
      float s = bl[t];
      for (int m = 0; m < D; ++m) s += b2[m] * Wl[m * 2 + t];
      KBf[t] = s;
    }
    return;
  }
  blk -= 1;
  {                                                // convert x: 4 uint4/thread
    int64_t base = (int64_t)blk * 1024 + t;
    const float4* xs = (const float4*)x;
#pragma unroll
    for (int i = 0; i < 4; ++i) {
      int64_t idx = base + i * 256;
      if (idx < (int64_t)NN * D / 8) {
        float4 f0 = xs[idx * 2], f1 = xs[idx * 2 + 1];
        uint4 o;
        o.x = (unsigned)f2bf(f0.x) | ((unsigned)f2bf(f0.y) << 16);
        o.y = (unsigned)f2bf(f0.z) | ((unsigned)f2bf(f0.w) << 16);
        o.z = (unsigned)f2bf(f1.x) | ((unsigned)f2bf(f1.y) << 16);
        o.w = (unsigned)f2bf(f1.z) | ((unsigned)f2bf(f1.w) << 16);
        ((uint4*)xb)[idx] = o;
      }
    }
  }
}

// ------------------------------------------------ k_fusedA: LDS CSR -> gather (-> LDS tile) -> gemm1
// 1563 blocks x 256 threads; block owns the 32 nodes of its own fine bucket.
// One wave per 8 nodes (2 sub-rounds x 4), 8 row-loads in flight per lane.
// h0 lands in an XOR-swizzled LDS tile; gemm1: wave (row-half, nf-half) split,
// h1 (bf16, pre-BN) -> global + BN-stat atomics.
__global__ __launch_bounds__(256, 6) void k_fusedA(const unsigned short* __restrict__ xb,
                                                   const int* __restrict__ gcnt,
                                                   const unsigned* __restrict__ pairs,
                                                   const unsigned short* __restrict__ W1p,
                                                   const float* __restrict__ b1,
                                                   unsigned short* __restrict__ h1b,
                                                   float* __restrict__ stats) {
  __shared__ uint4 tile[32 * 16];                  // 8 KB: 32 rows x 128 bf16, swizzled
  __shared__ unsigned short cs[32 * BS];           // 3 KB adjacency
  __shared__ int cur[32];
  __shared__ float redS[D], redQ[D];
  int t = threadIdx.x, b = blockIdx.x;
  if (t < D) { redS[t] = 0.f; redQ[t] = 0.f; }
  if (t < 32) cur[t] = 0;
  __syncthreads();

  // ---------- phase 0: build 32-node CSR in LDS from this block's bucket
  int cnt = gcnt[b]; if (cnt > PCAP2) cnt = PCAP2;
  for (int i = t; i < cnt; i += 256) {
    unsigned u = pairs[b * PCAP2 + i];
    int dl = (u >> 16) & 31;
    int pos = atomicAdd(&cur[dl], 1);
    if (pos < BS) cs[dl * BS + pos] = (unsigned short)(u & 0xFFFFu);
  }
  __syncthreads();

  int w = t >> 6, lane = t & 63;
  int g = lane >> 4, l = lane & 15;
  const uint4* xv = (const uint4*)xb;
  const uint4* csv = (const uint4*)cs;             // 6 uint4 per node row (48 u16)

#define ACC8(v)                                     \
  { a0 += __uint_as_float((v).x << 16);             \
    a1 += __uint_as_float((v).x & 0xFFFF0000u);     \
    a2 += __uint_as_float((v).y << 16);             \
    a3 += __uint_as_float((v).y & 0xFFFF0000u);     \
    a4 += __uint_as_float((v).z << 16);             \
    a5 += __uint_as_float((v).z & 0xFFFF0000u);     \
    a6 += __uint_as_float((v).w << 16);             \
    a7 += __uint_as_float((v).w & 0xFFFF0000u); }
#define MSK(v, kk) { unsigned m_ = ((kk) < dcap) ? 0xFFFFFFFFu : 0u; \
                     (v).x &= m_; (v).y &= m_; (v).z &= m_; (v).w &= m_; }

  // ---------- phase 1: gather 8 nodes per wave (2 sub-rounds x 4 nodes)
  for (int sub = 0; sub < 2; ++sub) {
    int dl = w * 8 + sub * 4 + g;                  // block-local row == node&31
    int node = b * 32 + dl;
    float a0 = 0, a1 = 0, a2 = 0, a3 = 0, a4 = 0, a5 = 0, a6 = 0, a7 = 0;
    if (node < NN) {
      int dcap = cur[dl]; if (dcap > BS) dcap = BS;
      int maxd = dcap;
      maxd = max(maxd, __shfl_xor(maxd, 16));
      maxd = max(maxd, __shfl_xor(maxd, 32));      // wave-uniform trip bound
      int nit = (maxd + 7) >> 3;
      for (int it = 0; it < nit; ++it) {
        uint4 iv = csv[dl * 6 + it];               // 8 packed u16 indices (broadcast)
        int j0 = it * 8;
        unsigned i0 = iv.x & 0xFFFFu, i1 = iv.x >> 16;
        unsigned i2 = iv.y & 0xFFFFu, i3 = iv.y >> 16;
        unsigned i4 = iv.z & 0xFFFFu, i5 = iv.z >> 16;
        unsigned i6 = iv.w & 0xFFFFu, i7 = iv.w >> 16;
        uint4 v0 = xv[i0 * 16u + l];               // 8 rows in flight / lane
        uint4 v1 = xv[i1 * 16u + l];
        uint4 v2 = xv[i2 * 16u + l];
        uint4 v3 = xv[i3 * 16u + l];
        uint4 v4 = xv[i4 * 16u + l];
        uint4 v5 = xv[i5 * 16u + l];
        uint4 v6 = xv[i6 * 16u + l];
        uint4 v7 = xv[i7 * 16u + l];
        MSK(v0, j0) MSK(v1, j0 + 1) MSK(v2, j0 + 2) MSK(v3, j0 + 3)
        MSK(v4, j0 + 4) MSK(v5, j0 + 5) MSK(v6, j0 + 6) MSK(v7, j0 + 7)
        ACC8(v0) ACC8(v1) ACC8(v2) ACC8(v3)
        ACC8(v4) ACC8(v5) ACC8(v6) ACC8(v7)
      }
      {                                            // self term
        uint4 sv = xv[(unsigned)node * 16u + l];
        ACC8(sv)
      }
    }
    uint4 o;                                       // zeros for node >= NN
    o.x = (unsigned)f2bf(a0) | ((unsigned)f2bf(a1) << 16);
    o.y = (unsigned)f2bf(a2) | ((unsigned)f2bf(a3) << 16);
    o.z = (unsigned)f2bf(a4) | ((unsigned)f2bf(a5) << 16);
    o.w = (unsigned)f2bf(a6) | ((unsigned)f2bf(a7) << 16);
    tile[(dl * 16 + l) ^ (dl & 7)] = o;            // swizzled store (conflict-free)
  }
#undef ACC8
#undef MSK
  __syncthreads();

  // ---------- phase 2: gemm1 — wave (row-half th, nf-half nh) of the 32-row tile
  {
    int th = w >> 1, nh = w & 1;
    int rbt = th * 16 + l;
    short8 a[4];
#pragma unroll
    for (int ks = 0; ks < 4; ++ks)
      a[ks] = *(const short8*)&tile[(rbt * 16 + ks * 4 + g) ^ (l & 7)];

    f32x4 acc[4];
#pragma unroll
    for (int nfl = 0; nfl < 4; ++nfl) { f32x4 z = {0.f, 0.f, 0.f, 0.f}; acc[nfl] = z; }

    const short8* B = (const short8*)W1p;
#pragma unroll
    for (int ks = 0; ks < 4; ++ks)
#pragma unroll
      for (int nfl = 0; nfl < 4; ++nfl) {
        int nf = nh * 4 + nfl;
        acc[nfl] = __builtin_amdgcn_mfma_f32_16x16x32_bf16(a[ks], B[(ks * 8 + nf) * 64 + lane],
                                                           acc[nfl], 0, 0, 0);
      }

#pragma unroll
    for (int nfl = 0; nfl < 4; ++nfl) {
      int colc = (nh * 4 + nfl) * 16 + l;
      float bias = b1[colc];
      float ps = 0.f, pq = 0.f;
#pragma unroll
      for (int r = 0; r < 4; ++r) {
        int row = b * 32 + th * 16 + g * 4 + r;
        float v = fmaxf(acc[nfl][r] + bias, 0.f);
        if (row < NN) {
          h1b[(int64_t)row * D + colc] = f2bf(v);
          ps += v; pq += v * v;
        }
      }
      ps += __shfl_xor(ps, 16); ps += __shfl_xor(ps, 32);
      pq += __shfl_xor(pq, 16); pq += __shfl_xor(pq, 32);
      if (g == 0) { atomicAdd(&redS[colc], ps); atomicAdd(&redQ[colc], pq); }
    }
  }
  __syncthreads();
  if (t < D) {
    unsafeAtomicAdd(&stats[t], redS[t]);
    unsafeAtomicAdd(&stats[D + t], redQ[t]);
  }
}

// ------------------------------------------------ k_head: BN-fold + collapsed linear head (fp32)
// logits = BN(h1) @ C + KB,  C = W2@Wl (128x2), KB = b2@Wl + bl.
__global__ __launch_bounds__(256) void k_head(const unsigned short* __restrict__ h1b,
                                              const float* __restrict__ stats,
                                              const float* __restrict__ gamma,
                                              const float* __restrict__ beta,
                                              const float* __restrict__ Cf,
                                              const float* __restrict__ KBf,
                                              float* __restrict__ out) {
  __shared__ float sc_s[D], sh_s[D];
  __shared__ float2 c2_s[D];
  int t = threadIdx.x;
  if (t < D) {
    const float inv_n = 1.0f / (float)NN;
    float mean = stats[t] * inv_n;
    float var = stats[D + t] * inv_n - mean * mean;
    float sc = gamma[t] * rsqrtf(var + 1e-5f);
    sc_s[t] = sc;
    sh_s[t] = beta[t] - mean * sc;
    c2_s[t] = ((const float2*)Cf)[t];
  }
  __syncthreads();
  int node = blockIdx.x * 16 + (t >> 4);           // 3125 blocks * 16 = NN exact
  int l = t & 15;
  uint4 v = ((const uint4*)h1b)[node * 16 + l];
  int k0 = l * 8;
  float e0 = __uint_as_float(v.x << 16), e1 = __uint_as_float(v.x & 0xFFFF0000u);
  float e2 = __uint_as_float(v.y << 16), e3 = __uint_as_float(v.y & 0xFFFF0000u);
  float e4 = __uint_as_float(v.z << 16), e5 = __uint_as_float(v.z & 0xFFFF0000u);
  float e6 = __uint_as_float(v.w << 16), e7 = __uint_as_float(v.w & 0xFFFF0000u);
  float p0 = 0.f, p1 = 0.f;
#define HC(ej, jj) { float u_ = ej * sc_s[k0 + jj] + sh_s[k0 + jj];  \
                     float2 c_ = c2_s[k0 + jj];                      \
                     p0 += u_ * c_.x; p1 += u_ * c_.y; }
  HC(e0, 0) HC(e1, 1) HC(e2, 2) HC(e3, 3) HC(e4, 4) HC(e5, 5) HC(e6, 6) HC(e7, 7)
#undef HC
  p0 += __shfl_xor(p0, 1); p0 += __shfl_xor(p0, 2);
  p0 += __shfl_xor(p0, 4); p0 += __shfl_xor(p0, 8);
  p1 += __shfl_xor(p1, 1); p1 += __shfl_xor(p1, 2);
  p1 += __shfl_xor(p1, 4); p1 += __shfl_xor(p1, 8);
  if (l == 0) {
    float2 kb = ((const float2*)KBf)[0];
    ((float2*)out)[node] = make_float2(p0 + kb.x, p1 + kb.y);
  }
}

// ------------------------------------------------ launcher
extern "C" void kernel_launch(void* const* d_in, const int* in_sizes, int n_in,
                              void* d_out, int out_size, void* d_ws, size_t ws_size,
                              hipStream_t stream) {
  const float* x     = (const float*)d_in[0];
  const int*   ei    = (const int*)d_in[1];
  const float* W1    = (const float*)d_in[2];
  const float* b1    = (const float*)d_in[3];
  const float* gamma = (const float*)d_in[4];
  const float* beta  = (const float*)d_in[5];
  const float* W2    = (const float*)d_in[6];
  const float* b2    = (const float*)d_in[7];
  const float* Wl    = (const float*)d_in[8];
  const float* bl    = (const float*)d_in[9];
  float* out = (float*)d_out;

  // workspace layout (~30 MB)
  unsigned short* xb  = (unsigned short*)d_ws;            // NN*D
  unsigned short* h1b = xb + (int64_t)NN * D;             // NN*D
  unsigned short* W1p = h1b + (int64_t)NN * D;            // 16384
  float* Cf     = (float*)(W1p + 16384);                  // 256 floats (C = W2@Wl as float2[128])
  float* KBf    = Cf + 256;                               // 4 floats (2 used)
  float* stats  = KBf + 4;                                // 256 floats
  int* gcnt     = (int*)(stats + 256);                    // NB2 ints (contiguous: one memset)
  unsigned* pairs = (unsigned*)(gcnt + NB2);              // NB2*PCAP2 (~4 MB)

  hipMemsetAsync(stats, 0, (256 + NB2) * sizeof(int), stream);  // stats + gcnt
  k_prep<<<FA + WB1 + 1 + XB4, 256, 0, stream>>>(x, W1, W2, Wl, b2, bl, ei,
                                                 xb, W1p, Cf, KBf, gcnt, pairs);
  k_fusedA<<<NB2, 256, 0, stream>>>(xb, gcnt, pairs, W1p, b1, h1b, stats);
  k_head<<<NN / 16, 256, 0, stream>>>(h1b, stats, gamma, beta, Cf, KBf, out);
}

// Round 4
// 109.697 us; speedup vs baseline: 1.0992x; 1.0992x over previous
//
#include <hip/hip_runtime.h>
#include <cstdint>

#define NN 50000
#define NE 600000
#define D 128
#define NWAVE 3125          // NN/16 exact
#define BS 48               // slots per node (incl. self); P(deg>=47|Poi(12)) ~ 1e-13
#define NB2 1563            // fine buckets (dst>>5), 32 nodes each
#define PCAP2 640           // pairs per bucket: mean 384, sigma 19.6 -> 13-sigma margin
#define FA 147              // pass-A blocks: ceil(NE/4096)
#define WB1 16              // W1-pack blocks: 16384/1024
#define XB4 782             // x-convert blocks: ceil(800000/1024)

typedef __attribute__((ext_vector_type(8))) short short8;
typedef __attribute__((ext_vector_type(4))) float f32x4;
typedef __attribute__((ext_vector_type(4))) unsigned u32x4;

static __device__ __forceinline__ unsigned short f2bf(float f) {
  unsigned int u = __float_as_uint(f);
  unsigned int r = (u + 0x7FFFu + ((u >> 16) & 1u)) >> 16;   // RNE
  return (unsigned short)r;
}

// ------------------------------------------------ k_prep: fine edge binning + W1 pack + C/KB + x->bf16
__global__ __launch_bounds__(256) void k_prep(const float* __restrict__ x,
                                              const float* __restrict__ W1,
                                              const float* __restrict__ W2,
                                              const float* __restrict__ Wl,
                                              const float* __restrict__ b2,
                                              const float* __restrict__ bl,
                                              const int* __restrict__ ei,
                                              unsigned short* __restrict__ xb,
                                              unsigned short* __restrict__ W1p,
                                              float* __restrict__ Cf,
                                              float* __restrict__ KBf,
                                              int* __restrict__ gcnt,
                                              unsigned* __restrict__ pairs) {
  __shared__ int histA[NB2], baseA[NB2], curA[NB2];   // 18.3 KB
  int blk = blockIdx.x, t = threadIdx.x;
  if (blk < FA) {                                  // pass A: bin 4096 edges
    for (int i = t; i < NB2; i += 256) histA[i] = 0;
    __syncthreads();
    int e0 = blk * 4096 + t;
#pragma unroll
    for (int i = 0; i < 16; ++i) {
      int e = e0 + i * 256;
      if (e < NE) atomicAdd(&histA[ei[NE + e] >> 5], 1);
    }
    __syncthreads();
    for (int i = t; i < NB2; i += 256) {
      int h = histA[i];
      baseA[i] = h ? atomicAdd(&gcnt[i], h) : 0;
      curA[i] = 0;
    }
    __syncthreads();
#pragma unroll
    for (int i = 0; i < 16; ++i) {
      int e = e0 + i * 256;
      if (e < NE) {
        int s = ei[e];
        int d = ei[NE + e];
        int b = d >> 5;
        int p = baseA[b] + atomicAdd(&curA[b], 1);
        if (p < PCAP2) pairs[b * PCAP2 + p] = (unsigned)s | ((unsigned)(d & 31) << 16);
      }
    }
    return;
  }
  blk -= FA;
  if (blk < WB1) {                                 // pack W1: 4 items/thread
    int base = blk * 1024 + t;
#pragma unroll
    for (int i = 0; i < 4; ++i) {
      int rem = base + i * 256;                    // 0..16383
      int ks = rem >> 12;
      int nf = (rem >> 9) & 7;
      int l  = (rem >> 3) & 63;
      int j  = rem & 7;
      int k = ks * 32 + (l >> 4) * 8 + j;
      int n = nf * 16 + (l & 15);
      W1p[rem] = f2bf(W1[k * D + n]);
    }
    return;
  }
  blk -= WB1;
  if (blk == 0) {                                  // C = W2@Wl (fp32), KB = b2@Wl + bl
    {
      int k = t >> 1, c = t & 1;                   // 256 threads -> 128x2
      const float4* w2r = (const float4*)(W2 + k * D);
      float s = 0.f;
#pragma unroll
      for (int m4 = 0; m4 < 32; ++m4) {
        float4 wv = w2r[m4];
        int m = m4 * 4;
        s += wv.x * Wl[(m + 0) * 2 + c] + wv.y * Wl[(m + 1) * 2 + c] +
             wv.z * Wl[(m + 2) * 2 + c] + wv.w * Wl[(m + 3) * 2 + c];
      }
      Cf[k * 2 + c] = s;
    }
    if (t < 2) {
      float s = bl[t];
      for (int m = 0; m < D; ++m) s += b2[m] * Wl[m * 2 + t];
      KBf[t] = s;
    }
    return;
  }
  blk -= 1;
  {                                                // convert x: 4 uint4/thread
    int64_t base = (int64_t)blk * 1024 + t;
    const float4* xs = (const float4*)x;
#pragma unroll
    for (int i = 0; i < 4; ++i) {
      int64_t idx = base + i * 256;
      if (idx < (int64_t)NN * D / 8) {
        float4 f0 = xs[idx * 2], f1 = xs[idx * 2 + 1];
        uint4 o;
        o.x = (unsigned)f2bf(f0.x) | ((unsigned)f2bf(f0.y) << 16);
        o.y = (unsigned)f2bf(f0.z) | ((unsigned)f2bf(f0.w) << 16);
        o.z = (unsigned)f2bf(f1.x) | ((unsigned)f2bf(f1.y) << 16);
        o.w = (unsigned)f2bf(f1.z) | ((unsigned)f2bf(f1.w) << 16);
        ((uint4*)xb)[idx] = o;
      }
    }
  }
}

// ------------------------------------------------ k_gather: column-sliced, XCD-L2-resident
// Grid = NB2*4; bid -> (bucket b = bid>>2, slice q = bid&3). With round-robin
// workgroup->XCD (xcd = bid%8), slice q lands only on XCDs {q, q+4}; each XCD
// streams a 3.2 MB column slice of xb that FITS its 4 MB private L2.
// Block: rebuild 32-node CSR in LDS (self appended), then each 4-lane group
// accumulates one (node, edge-slot-pair) stream of 64 B row-slices.
// Masked slots select index 0 BEFORE the load (R3 bug: garbage indices).
// h0 slice written complete (no cross-slice reduction) via non-temporal stores.
__global__ __launch_bounds__(256, 6) void k_gather(const unsigned short* __restrict__ xb,
                                                   const int* __restrict__ gcnt,
                                                   const unsigned* __restrict__ pairs,
                                                   unsigned short* __restrict__ h0b) {
  __shared__ unsigned short cs[32 * BS];           // 3 KB adjacency (+self)
  __shared__ int cur[32];
  int t = threadIdx.x, bid = blockIdx.x;
  int q = bid & 3, b = bid >> 2;
  if (t < 32) cur[t] = 0;
  __syncthreads();

  // phase 0: build this bucket's 32-node CSR in LDS
  int cnt = gcnt[b]; if (cnt > PCAP2) cnt = PCAP2;
  for (int i = t; i < cnt; i += 256) {
    unsigned u = pairs[b * PCAP2 + i];
    int dl = (u >> 16) & 31;
    int pos = atomicAdd(&cur[dl], 1);
    if (pos < BS - 1) cs[dl * BS + pos] = (unsigned short)(u & 0xFFFFu);
  }
  __syncthreads();
  if (t < 32) {                                    // append self term to CSR
    int node = b * 32 + t;
    int pos = cur[t]; if (pos > BS - 1) pos = BS - 1;
    if (node < NN) { cs[t * BS + pos] = (unsigned short)node; cur[t] = pos + 1; }
    else cur[t] = 0;
  }
  __syncthreads();

  int lane = t & 63, w = t >> 6;
  int grp = lane >> 2, c = lane & 3;               // 16 groups of 4 lanes
  int dl = w * 8 + (grp & 7);                      // node-local row (8 nodes/wave)
  int sset = grp >> 3;                             // slot-set 0/1 (2 groups per node)
  int node = b * 32 + dl;
  int dcap = cur[dl];
  int maxd = dcap;
  maxd = max(maxd, __shfl_xor(maxd, 4));
  maxd = max(maxd, __shfl_xor(maxd, 8));
  maxd = max(maxd, __shfl_xor(maxd, 16));          // wave-uniform trip bound
  int nit = (maxd + 3) >> 2;                       // 4 slots/node/iter
  const uint4* xv = (const uint4*)xb;
  int co = q * 4 + c;                              // uint4 column within the row
  int sbase = dl * BS;
  float a0 = 0, a1 = 0, a2 = 0, a3 = 0, a4 = 0, a5 = 0, a6 = 0, a7 = 0;
#define ACC8(v)                                     \
  { a0 += __uint_as_float((v).x << 16);             \
    a1 += __uint_as_float((v).x & 0xFFFF0000u);     \
    a2 += __uint_as_float((v).y << 16);             \
    a3 += __uint_as_float((v).y & 0xFFFF0000u);     \
    a4 += __uint_as_float((v).z << 16);             \
    a5 += __uint_as_float((v).z & 0xFFFF0000u);     \
    a6 += __uint_as_float((v).w << 16);             \
    a7 += __uint_as_float((v).w & 0xFFFF0000u); }
  for (int it = 0; it < nit; ++it) {
    int k0 = it * 4 + sset * 2;
    int k1 = k0 + 1;
    unsigned i0 = (k0 < dcap) ? (unsigned)cs[sbase + k0] : 0u;  // select BEFORE load
    unsigned i1 = (k1 < dcap) ? (unsigned)cs[sbase + k1] : 0u;
    uint4 v0 = xv[i0 * 16u + co];
    uint4 v1 = xv[i1 * 16u + co];
    unsigned m0 = (k0 < dcap) ? 0xFFFFFFFFu : 0u;
    unsigned m1 = (k1 < dcap) ? 0xFFFFFFFFu : 0u;
    v0.x &= m0; v0.y &= m0; v0.z &= m0; v0.w &= m0;
    v1.x &= m1; v1.y &= m1; v1.z &= m1; v1.w &= m1;
    ACC8(v0) ACC8(v1)
  }
#undef ACC8
  a0 += __shfl_xor(a0, 32); a1 += __shfl_xor(a1, 32);
  a2 += __shfl_xor(a2, 32); a3 += __shfl_xor(a3, 32);
  a4 += __shfl_xor(a4, 32); a5 += __shfl_xor(a5, 32);
  a6 += __shfl_xor(a6, 32); a7 += __shfl_xor(a7, 32);
  if (sset == 0 && node < NN) {
    u32x4 o;
    o.x = (unsigned)f2bf(a0) | ((unsigned)f2bf(a1) << 16);
    o.y = (unsigned)f2bf(a2) | ((unsigned)f2bf(a3) << 16);
    o.z = (unsigned)f2bf(a4) | ((unsigned)f2bf(a5) << 16);
    o.w = (unsigned)f2bf(a6) | ((unsigned)f2bf(a7) << 16);
    __builtin_nontemporal_store(o, (u32x4*)h0b + (int64_t)node * 16 + co);
  }
}

// ------------------------------------------------ gemm1 (MFMA): h1b = bf16(relu(h0b@W1+b1)), col stats
__global__ __launch_bounds__(256) void k_gemm1(const unsigned short* __restrict__ h0b,
                                               const unsigned short* __restrict__ W1p,
                                               const float* __restrict__ b1,
                                               unsigned short* __restrict__ h1b,
                                               float* __restrict__ stats) {
  __shared__ float redS[D], redQ[D];
  int t = threadIdx.x;
  if (t < D) { redS[t] = 0.f; redQ[t] = 0.f; }
  __syncthreads();
  int w = t >> 6, lane = t & 63;
  int wave_id = blockIdx.x * 4 + w;
  bool valid = wave_id < NWAVE;
  int l = lane & 15, g = lane >> 4;
  int row0 = wave_id * 16;

  if (valid) {
    short8 a[4];
    const short8* A = (const short8*)h0b;         // 16 frags per row
#pragma unroll
    for (int ks = 0; ks < 4; ++ks)
      a[ks] = A[(int64_t)(row0 + l) * 16 + ks * 4 + g];

    f32x4 acc[8];
#pragma unroll
    for (int nf = 0; nf < 8; ++nf) { f32x4 z = {0.f, 0.f, 0.f, 0.f}; acc[nf] = z; }

    const short8* B = (const short8*)W1p;
#pragma unroll
    for (int ks = 0; ks < 4; ++ks)
#pragma unroll
      for (int nf = 0; nf < 8; ++nf)
        acc[nf] = __builtin_amdgcn_mfma_f32_16x16x32_bf16(a[ks], B[(ks * 8 + nf) * 64 + lane],
                                                          acc[nf], 0, 0, 0);

#pragma unroll
    for (int nf = 0; nf < 8; ++nf) {
      int colc = nf * 16 + l;
      float bias = b1[colc];
      float ps = 0.f, pq = 0.f;
#pragma unroll
      for (int r = 0; r < 4; ++r) {
        float v = fmaxf(acc[nf][r] + bias, 0.f);
        int row = row0 + g * 4 + r;
        h1b[(int64_t)row * D + colc] = f2bf(v);
        ps += v; pq += v * v;
      }
      ps += __shfl_xor(ps, 16); ps += __shfl_xor(ps, 32);
      pq += __shfl_xor(pq, 16); pq += __shfl_xor(pq, 32);
      if (g == 0) { atomicAdd(&redS[colc], ps); atomicAdd(&redQ[colc], pq); }
    }
  }
  __syncthreads();
  if (t < D) {
    unsafeAtomicAdd(&stats[t], redS[t]);
    unsafeAtomicAdd(&stats[D + t], redQ[t]);
  }
}

// ------------------------------------------------ k_head: BN-fold + collapsed linear head (fp32)
// logits = BN(h1) @ C + KB,  C = W2@Wl (128x2), KB = b2@Wl + bl.
__global__ __launch_bounds__(256) void k_head(const unsigned short* __restrict__ h1b,
                                              const float* __restrict__ stats,
                                              const float* __restrict__ gamma,
                                              const float* __restrict__ beta,
                                              const float* __restrict__ Cf,
                                              const float* __restrict__ KBf,
                                              float* __restrict__ out) {
  __shared__ float sc_s[D], sh_s[D];
  __shared__ float2 c2_s[D];
  int t = threadIdx.x;
  if (t < D) {
    const float inv_n = 1.0f / (float)NN;
    float mean = stats[t] * inv_n;
    float var = stats[D + t] * inv_n - mean * mean;
    float sc = gamma[t] * rsqrtf(var + 1e-5f);
    sc_s[t] = sc;
    sh_s[t] = beta[t] - mean * sc;
    c2_s[t] = ((const float2*)Cf)[t];
  }
  __syncthreads();
  int node = blockIdx.x * 16 + (t >> 4);           // 3125 blocks * 16 = NN exact
  int l = t & 15;
  uint4 v = ((const uint4*)h1b)[node * 16 + l];
  int k0 = l * 8;
  float e0 = __uint_as_float(v.x << 16), e1 = __uint_as_float(v.x & 0xFFFF0000u);
  float e2 = __uint_as_float(v.y << 16), e3 = __uint_as_float(v.y & 0xFFFF0000u);
  float e4 = __uint_as_float(v.z << 16), e5 = __uint_as_float(v.z & 0xFFFF0000u);
  float e6 = __uint_as_float(v.w << 16), e7 = __uint_as_float(v.w & 0xFFFF0000u);
  float p0 = 0.f, p1 = 0.f;
#define HC(ej, jj) { float u_ = ej * sc_s[k0 + jj] + sh_s[k0 + jj];  \
                     float2 c_ = c2_s[k0 + jj];                      \
                     p0 += u_ * c_.x; p1 += u_ * c_.y; }
  HC(e0, 0) HC(e1, 1) HC(e2, 2) HC(e3, 3) HC(e4, 4) HC(e5, 5) HC(e6, 6) HC(e7, 7)
#undef HC
  p0 += __shfl_xor(p0, 1); p0 += __shfl_xor(p0, 2);
  p0 += __shfl_xor(p0, 4); p0 += __shfl_xor(p0, 8);
  p1 += __shfl_xor(p1, 1); p1 += __shfl_xor(p1, 2);
  p1 += __shfl_xor(p1, 4); p1 += __shfl_xor(p1, 8);
  if (l == 0) {
    float2 kb = ((const float2*)KBf)[0];
    ((float2*)out)[node] = make_float2(p0 + kb.x, p1 + kb.y);
  }
}

// ------------------------------------------------ launcher
extern "C" void kernel_launch(void* const* d_in, const int* in_sizes, int n_in,
                              void* d_out, int out_size, void* d_ws, size_t ws_size,
                              hipStream_t stream) {
  const float* x     = (const float*)d_in[0];
  const int*   ei    = (const int*)d_in[1];
  const float* W1    = (const float*)d_in[2];
  const float* b1    = (const float*)d_in[3];
  const float* gamma = (const float*)d_in[4];
  const float* beta  = (const float*)d_in[5];
  const float* W2    = (const float*)d_in[6];
  const float* b2    = (const float*)d_in[7];
  const float* Wl    = (const float*)d_in[8];
  const float* bl    = (const float*)d_in[9];
  float* out = (float*)d_out;

  // workspace layout (~43 MB)
  unsigned short* xb  = (unsigned short*)d_ws;            // NN*D
  unsigned short* h0b = xb + (int64_t)NN * D;             // NN*D
  unsigned short* h1b = h0b + (int64_t)NN * D;            // NN*D
  unsigned short* W1p = h1b + (int64_t)NN * D;            // 16384
  float* Cf     = (float*)(W1p + 16384);                  // 256 floats (C = W2@Wl as float2[128])
  float* KBf    = Cf + 256;                               // 4 floats (2 used)
  float* stats  = KBf + 4;                                // 256 floats
  int* gcnt     = (int*)(stats + 256);                    // NB2 ints (contiguous: one memset)
  unsigned* pairs = (unsigned*)(gcnt + NB2);              // NB2*PCAP2 (~4 MB)

  hipMemsetAsync(stats, 0, (256 + NB2) * sizeof(int), stream);  // stats + gcnt
  k_prep<<<FA + WB1 + 1 + XB4, 256, 0, stream>>>(x, W1, W2, Wl, b2, bl, ei,
                                                 xb, W1p, Cf, KBf, gcnt, pairs);
  k_gather<<<NB2 * 4, 256, 0, stream>>>(xb, gcnt, pairs, h0b);
  k_gemm1<<<(NWAVE + 3) / 4, 256, 0, stream>>>(h0b, W1p, b1, h1b, stats);
  k_head<<<NN / 16, 256, 0, stream>>>(h1b, stats, gamma, beta, Cf, KBf, out);
}

// Round 5
// 104.506 us; speedup vs baseline: 1.1538x; 1.0497x over previous
//
#include <hip/hip_runtime.h>
#include <cstdint>

#define NN 50000
#define NN4 200000          // uint4 chunks per plane (NN*4)
#define NE 600000
#define D 128
#define NWAVE 3125          // NN/16 exact
#define BS 48               // slots per node (incl. self)
#define NB2 1563            // fine buckets (dst>>5), 32 nodes each
#define NPADG 50048         // padded node rows for colw (782*64)
#define PCAP2 640           // pairs per bucket: mean 384, sigma 19.6 -> 13-sigma margin
#define FA 147              // pass-A blocks: ceil(NE/4096)
#define WB1 16              // W1-pack blocks: 16384/1024
#define XB4 782             // x-convert blocks: ceil(800000/1024)

typedef __attribute__((ext_vector_type(8))) short short8;
typedef __attribute__((ext_vector_type(4))) float f32x4;

static __device__ __forceinline__ unsigned short f2bf(float f) {
  unsigned int u = __float_as_uint(f);
  unsigned int r = (u + 0x7FFFu + ((u >> 16) & 1u)) >> 16;   // RNE
  return (unsigned short)r;
}

// ------------------------------------------------ k_prep: fine edge binning + W1 pack + C/KB + x->planes
//  x is converted into 4 SLICE-MAJOR planes: plane q = cols [q*32, q*32+32) of all rows,
//  3.2 MB each -> line-aligned, fits one XCD L2 (R4 failure: row-major slices shared
//  128B lines across XCDs -> 2x footprint, no residency).
__global__ __launch_bounds__(256) void k_prep(const float* __restrict__ x,
                                              const float* __restrict__ W1,
                                              const float* __restrict__ W2,
                                              const float* __restrict__ Wl,
                                              const float* __restrict__ b2,
                                              const float* __restrict__ bl,
                                              const int* __restrict__ ei,
                                              unsigned short* __restrict__ xb,
                                              unsigned short* __restrict__ W1p,
                                              float* __restrict__ Cf,
                                              float* __restrict__ KBf,
                                              int* __restrict__ gcnt,
                                              unsigned* __restrict__ pairs) {
  __shared__ int histA[NB2], baseA[NB2], curA[NB2];   // 18.3 KB
  int blk = blockIdx.x, t = threadIdx.x;
  if (blk < FA) {                                  // pass A: bin 4096 edges
    for (int i = t; i < NB2; i += 256) histA[i] = 0;
    __syncthreads();
    int e0 = blk * 4096 + t;
#pragma unroll
    for (int i = 0; i < 16; ++i) {
      int e = e0 + i * 256;
      if (e < NE) atomicAdd(&histA[ei[NE + e] >> 5], 1);
    }
    __syncthreads();
    for (int i = t; i < NB2; i += 256) {
      int h = histA[i];
      baseA[i] = h ? atomicAdd(&gcnt[i], h) : 0;
      curA[i] = 0;
    }
    __syncthreads();
#pragma unroll
    for (int i = 0; i < 16; ++i) {
      int e = e0 + i * 256;
      if (e < NE) {
        int s = ei[e];
        int d = ei[NE + e];
        int b = d >> 5;
        int p = baseA[b] + atomicAdd(&curA[b], 1);
        if (p < PCAP2) pairs[b * PCAP2 + p] = (unsigned)s | ((unsigned)(d & 31) << 16);
      }
    }
    return;
  }
  blk -= FA;
  if (blk < WB1) {                                 // pack W1: 4 items/thread
    int base = blk * 1024 + t;
#pragma unroll
    for (int i = 0; i < 4; ++i) {
      int rem = base + i * 256;                    // 0..16383
      int ks = rem >> 12;
      int nf = (rem >> 9) & 7;
      int l  = (rem >> 3) & 63;
      int j  = rem & 7;
      int k = ks * 32 + (l >> 4) * 8 + j;
      int n = nf * 16 + (l & 15);
      W1p[rem] = f2bf(W1[k * D + n]);
    }
    return;
  }
  blk -= WB1;
  if (blk == 0) {                                  // C = W2@Wl (fp32), KB = b2@Wl + bl
    {
      int k = t >> 1, c = t & 1;                   // 256 threads -> 128x2
      const float4* w2r = (const float4*)(W2 + k * D);
      float s = 0.f;
#pragma unroll
      for (int m4 = 0; m4 < 32; ++m4) {
        float4 wv = w2r[m4];
        int m = m4 * 4;
        s += wv.x * Wl[(m + 0) * 2 + c] + wv.y * Wl[(m + 1) * 2 + c] +
             wv.z * Wl[(m + 2) * 2 + c] + wv.w * Wl[(m + 3) * 2 + c];
      }
      Cf[k * 2 + c] = s;
    }
    if (t < 2) {
      float s = bl[t];
      for (int m = 0; m < D; ++m) s += b2[m] * Wl[m * 2 + t];
      KBf[t] = s;
    }
    return;
  }
  blk -= 1;
  {                                                // convert x -> slice-major planes
    int64_t base = (int64_t)blk * 1024 + t;
    const float4* xs = (const float4*)x;
#pragma unroll
    for (int i = 0; i < 4; ++i) {
      int64_t idx = base + i * 256;                // flat uint4 id: row*16 + co
      if (idx < (int64_t)NN * D / 8) {
        float4 f0 = xs[idx * 2], f1 = xs[idx * 2 + 1];
        uint4 o;
        o.x = (unsigned)f2bf(f0.x) | ((unsigned)f2bf(f0.y) << 16);
        o.y = (unsigned)f2bf(f0.z) | ((unsigned)f2bf(f0.w) << 16);
        o.z = (unsigned)f2bf(f1.x) | ((unsigned)f2bf(f1.y) << 16);
        o.w = (unsigned)f2bf(f1.z) | ((unsigned)f2bf(f1.w) << 16);
        int64_t row = idx >> 4;
        int co = (int)(idx & 15);
        ((uint4*)xb)[(int64_t)(co >> 2) * NN4 + row * 4 + (co & 3)] = o;
      }
    }
  }
}

// ------------------------------------------------ k_fill: per-bucket LDS CSR build (+self) + flush
// 1563 blocks; 32 nodes each. colw row = 48 u16 (self appended); cursor = total count.
__global__ __launch_bounds__(256) void k_fill(const unsigned* __restrict__ pairs,
                                              const int* __restrict__ gcnt,
                                              unsigned short* __restrict__ colw,
                                              int* __restrict__ cursor) {
  __shared__ unsigned short cs[32 * BS];           // 3 KB
  __shared__ int cur[32];
  int b = blockIdx.x, t = threadIdx.x;
  if (t < 32) cur[t] = 0;
  __syncthreads();
  int cnt = gcnt[b]; if (cnt > PCAP2) cnt = PCAP2;
  for (int i = t; i < cnt; i += 256) {
    unsigned u = pairs[b * PCAP2 + i];
    int dl = (u >> 16) & 31;
    int pos = atomicAdd(&cur[dl], 1);
    if (pos < BS - 1) cs[dl * BS + pos] = (unsigned short)(u & 0xFFFFu);  // slot 47 reserved for self
  }
  __syncthreads();
  if (t < 32) {                                    // append self term
    int node = b * 32 + t;
    if (node < NN) {
      int pos = cur[t]; if (pos > BS - 1) pos = BS - 1;
      cs[t * BS + pos] = (unsigned short)node;
      cur[t] = pos + 1;
    } else cur[t] = 0;
    cursor[node] = cur[t];
  }
  __syncthreads();
  uint4* dst = (uint4*)(colw + (size_t)b * 32 * BS);    // 3072 B = 192 uint4
  const uint4* src = (const uint4*)cs;
  for (int i = t; i < 192; i += 256) dst[i] = src[i];
}

// ------------------------------------------------ k_gather: slice-plane gather, L2-resident
// Grid = 782*4; bid -> (slice q = bid&3, node-block nb = bid>>2). Round-robin
// dispatch puts slice q on XCDs {q,q+4}; plane q (3.2 MB) fits their L2s.
// Block: memcpy 64 nodes' CSR (6 KB) to LDS; each 4-lane group owns one node;
// per iter: 4 slots, lane c loads 16B chunk c of each slot -> 4 loads in
// flight/lane, lane owns cols c*8..c*8+7 -> no cross-lane reduction.
__global__ __launch_bounds__(256) void k_gather(const unsigned short* __restrict__ xb,
                                                const int* __restrict__ cursor,
                                                const unsigned short* __restrict__ colw,
                                                unsigned short* __restrict__ h0b) {
  __shared__ uint4 cs4[384];                       // 64 nodes x 48 u16 = 6 KB
  int t = threadIdx.x, bid = blockIdx.x;
  int q = bid & 3, nb = bid >> 2;
  const uint4* srcw = (const uint4*)(colw + (size_t)nb * 64 * BS);
  for (int i = t; i < 384; i += 256) cs4[i] = srcw[i];
  __syncthreads();

  int lane = t & 63, w = t >> 6;
  int grp = lane >> 2, c = lane & 3;
  int nl = w * 16 + grp;                           // block-local node 0..63
  int node = nb * 64 + nl;
  int dcap = (node < NN) ? cursor[node] : 0;
  const uint4* xq = (const uint4*)xb + (size_t)q * NN4;
  const uint2* csv = (const uint2*)cs4;            // 12 uint2 per node row

  float a0 = 0, a1 = 0, a2 = 0, a3 = 0, a4 = 0, a5 = 0, a6 = 0, a7 = 0;
#define ACC8(v)                                     \
  { a0 += __uint_as_float((v).x << 16);             \
    a1 += __uint_as_float((v).x & 0xFFFF0000u);     \
    a2 += __uint_as_float((v).y << 16);             \
    a3 += __uint_as_float((v).y & 0xFFFF0000u);     \
    a4 += __uint_as_float((v).z << 16);             \
    a5 += __uint_as_float((v).z & 0xFFFF0000u);     \
    a6 += __uint_as_float((v).w << 16);             \
    a7 += __uint_as_float((v).w & 0xFFFF0000u); }
  int nit = (dcap + 3) >> 2;
  for (int it = 0; it < nit; ++it) {
    uint2 iv = csv[nl * 12 + it];                  // 4 packed u16 slot indices (broadcast)
    int k0 = it * 4;
    unsigned i0 = iv.x & 0xFFFFu, i1 = iv.x >> 16;
    unsigned i2 = iv.y & 0xFFFFu, i3 = iv.y >> 16;
    i0 = (k0     < dcap) ? i0 : 0u;                // select BEFORE load (R3 lesson)
    i1 = (k0 + 1 < dcap) ? i1 : 0u;
    i2 = (k0 + 2 < dcap) ? i2 : 0u;
    i3 = (k0 + 3 < dcap) ? i3 : 0u;
    uint4 v0 = xq[i0 * 4u + c];                    // 4 x 16B in flight per lane
    uint4 v1 = xq[i1 * 4u + c];
    uint4 v2 = xq[i2 * 4u + c];
    uint4 v3 = xq[i3 * 4u + c];
    unsigned m0 = (k0     < dcap) ? 0xFFFFFFFFu : 0u;
    unsigned m1 = (k0 + 1 < dcap) ? 0xFFFFFFFFu : 0u;
    unsigned m2 = (k0 + 2 < dcap) ? 0xFFFFFFFFu : 0u;
    unsigned m3 = (k0 + 3 < dcap) ? 0xFFFFFFFFu : 0u;
    v0.x &= m0; v0.y &= m0; v0.z &= m0; v0.w &= m0;
    v1.x &= m1; v1.y &= m1; v1.z &= m1; v1.w &= m1;
    v2.x &= m2; v2.y &= m2; v2.z &= m2; v2.w &= m2;
    v3.x &= m3; v3.y &= m3; v3.z &= m3; v3.w &= m3;
    ACC8(v0) ACC8(v1) ACC8(v2) ACC8(v3)
  }
#undef ACC8
  if (node < NN) {                                 // regular store: keep h0 in L2 (R4 lesson)
    uint4 o;
    o.x = (unsigned)f2bf(a0) | ((unsigned)f2bf(a1) << 16);
    o.y = (unsigned)f2bf(a2) | ((unsigned)f2bf(a3) << 16);
    o.z = (unsigned)f2bf(a4) | ((unsigned)f2bf(a5) << 16);
    o.w = (unsigned)f2bf(a6) | ((unsigned)f2bf(a7) << 16);
    ((uint4*)h0b)[(size_t)q * NN4 + (size_t)node * 4 + c] = o;
  }
}

// ------------------------------------------------ gemm1 (MFMA): h1b = bf16(relu(h0@W1+b1)), col stats
// A-fragment a[ks] lives entirely in h0 plane ks (cols ks*32+g*8..+7 = chunk g).
__global__ __launch_bounds__(256) void k_gemm1(const unsigned short* __restrict__ h0b,
                                               const unsigned short* __restrict__ W1p,
                                               const float* __restrict__ b1,
                                               unsigned short* __restrict__ h1b,
                                               float* __restrict__ stats) {
  __shared__ float redS[D], redQ[D];
  int t = threadIdx.x;
  if (t < D) { redS[t] = 0.f; redQ[t] = 0.f; }
  __syncthreads();
  int w = t >> 6, lane = t & 63;
  int wave_id = blockIdx.x * 4 + w;
  bool valid = wave_id < NWAVE;
  int l = lane & 15, g = lane >> 4;
  int row0 = wave_id * 16;

  if (valid) {
    short8 a[4];
    const short8* A = (const short8*)h0b;
#pragma unroll
    for (int ks = 0; ks < 4; ++ks)
      a[ks] = A[(int64_t)ks * NN4 + (int64_t)(row0 + l) * 4 + g];

    f32x4 acc[8];
#pragma unroll
    for (int nf = 0; nf < 8; ++nf) { f32x4 z = {0.f, 0.f, 0.f, 0.f}; acc[nf] = z; }

    const short8* B = (const short8*)W1p;
#pragma unroll
    for (int ks = 0; ks < 4; ++ks)
#pragma unroll
      for (int nf = 0; nf < 8; ++nf)
        acc[nf] = __builtin_amdgcn_mfma_f32_16x16x32_bf16(a[ks], B[(ks * 8 + nf) * 64 + lane],
                                                          acc[nf], 0, 0, 0);

#pragma unroll
    for (int nf = 0; nf < 8; ++nf) {
      int colc = nf * 16 + l;
      float bias = b1[colc];
      float ps = 0.f, pq = 0.f;
#pragma unroll
      for (int r = 0; r < 4; ++r) {
        float v = fmaxf(acc[nf][r] + bias, 0.f);
        int row = row0 + g * 4 + r;
        h1b[(int64_t)row * D + colc] = f2bf(v);
        ps += v; pq += v * v;
      }
      ps += __shfl_xor(ps, 16); ps += __shfl_xor(ps, 32);
      pq += __shfl_xor(pq, 16); pq += __shfl_xor(pq, 32);
      if (g == 0) { atomicAdd(&redS[colc], ps); atomicAdd(&redQ[colc], pq); }
    }
  }
  __syncthreads();
  if (t < D) {
    unsafeAtomicAdd(&stats[t], redS[t]);
    unsafeAtomicAdd(&stats[D + t], redQ[t]);
  }
}

// ------------------------------------------------ k_head: BN-fold + collapsed linear head (fp32)
__global__ __launch_bounds__(256) void k_head(const unsigned short* __restrict__ h1b,
                                              const float* __restrict__ stats,
                                              const float* __restrict__ gamma,
                                              const float* __restrict__ beta,
                                              const float* __restrict__ Cf,
                                              const float* __restrict__ KBf,
                                              float* __restrict__ out) {
  __shared__ float sc_s[D], sh_s[D];
  __shared__ float2 c2_s[D];
  int t = threadIdx.x;
  if (t < D) {
    const float inv_n = 1.0f / (float)NN;
    float mean = stats[t] * inv_n;
    float var = stats[D + t] * inv_n - mean * mean;
    float sc = gamma[t] * rsqrtf(var + 1e-5f);
    sc_s[t] = sc;
    sh_s[t] = beta[t] - mean * sc;
    c2_s[t] = ((const float2*)Cf)[t];
  }
  __syncthreads();
  int node = blockIdx.x * 16 + (t >> 4);           // 3125 blocks * 16 = NN exact
  int l = t & 15;
  uint4 v = ((const uint4*)h1b)[node * 16 + l];
  int k0 = l * 8;
  float e0 = __uint_as_float(v.x << 16), e1 = __uint_as_float(v.x & 0xFFFF0000u);
  float e2 = __uint_as_float(v.y << 16), e3 = __uint_as_float(v.y & 0xFFFF0000u);
  float e4 = __uint_as_float(v.z << 16), e5 = __uint_as_float(v.z & 0xFFFF0000u);
  float e6 = __uint_as_float(v.w << 16), e7 = __uint_as_float(v.w & 0xFFFF0000u);
  float p0 = 0.f, p1 = 0.f;
#define HC(ej, jj) { float u_ = ej * sc_s[k0 + jj] + sh_s[k0 + jj];  \
                     float2 c_ = c2_s[k0 + jj];                      \
                     p0 += u_ * c_.x; p1 += u_ * c_.y; }
  HC(e0, 0) HC(e1, 1) HC(e2, 2) HC(e3, 3) HC(e4, 4) HC(e5, 5) HC(e6, 6) HC(e7, 7)
#undef HC
  p0 += __shfl_xor(p0, 1); p0 += __shfl_xor(p0, 2);
  p0 += __shfl_xor(p0, 4); p0 += __shfl_xor(p0, 8);
  p1 += __shfl_xor(p1, 1); p1 += __shfl_xor(p1, 2);
  p1 += __shfl_xor(p1, 4); p1 += __shfl_xor(p1, 8);
  if (l == 0) {
    float2 kb = ((const float2*)KBf)[0];
    ((float2*)out)[node] = make_float2(p0 + kb.x, p1 + kb.y);
  }
}

// ------------------------------------------------ launcher
extern "C" void kernel_launch(void* const* d_in, const int* in_sizes, int n_in,
                              void* d_out, int out_size, void* d_ws, size_t ws_size,
                              hipStream_t stream) {
  const float* x     = (const float*)d_in[0];
  const int*   ei    = (const int*)d_in[1];
  const float* W1    = (const float*)d_in[2];
  const float* b1    = (const float*)d_in[3];
  const float* gamma = (const float*)d_in[4];
  const float* beta  = (const float*)d_in[5];
  const float* W2    = (const float*)d_in[6];
  const float* b2    = (const float*)d_in[7];
  const float* Wl    = (const float*)d_in[8];
  const float* bl    = (const float*)d_in[9];
  float* out = (float*)d_out;

  // workspace layout (~48 MB), 16B-aligned segments first
  unsigned short* xb  = (unsigned short*)d_ws;            // NN*D (4 slice planes)
  unsigned short* h0b = xb + (int64_t)NN * D;             // NN*D (4 slice planes)
  unsigned short* h1b = h0b + (int64_t)NN * D;            // NN*D (row-major)
  unsigned short* W1p = h1b + (int64_t)NN * D;            // 16384
  unsigned short* colw = W1p + 16384;                     // NPADG*BS u16 (~4.8 MB)
  int* cursor   = (int*)(colw + (size_t)NPADG * BS);      // NPADG ints
  float* Cf     = (float*)(cursor + NPADG);               // 256 floats
  float* KBf    = Cf + 256;                               // 4 floats
  float* stats  = KBf + 4;                                // 256 floats
  int* gcnt     = (int*)(stats + 256);                    // NB2 ints (contiguous with stats)
  unsigned* pairs = (unsigned*)(gcnt + NB2);              // NB2*PCAP2 (~4 MB)

  hipMemsetAsync(stats, 0, (256 + NB2) * sizeof(int), stream);  // stats + gcnt
  k_prep<<<FA + WB1 + 1 + XB4, 256, 0, stream>>>(x, W1, W2, Wl, b2, bl, ei,
                                                 xb, W1p, Cf, KBf, gcnt, pairs);
  k_fill<<<NB2, 256, 0, stream>>>(pairs, gcnt, colw, cursor);
  k_gather<<<782 * 4, 256, 0, stream>>>(xb, cursor, colw, h0b);
  k_gemm1<<<(NWAVE + 3) / 4, 256, 0, stream>>>(h0b, W1p, b1, h1b, stats);
  k_head<<<NN / 16, 256, 0, stream>>>(h1b, stats, gamma, beta, Cf, KBf, out);
}

// Round 6
// 75.197 us; speedup vs baseline: 1.6035x; 1.3898x over previous
//
#include <hip/hip_runtime.h>
#include <cstdint>

#define NN 50000
#define NE 600000
#define D 128
#define NPAD 50176          // 196*256 >= NN+1
#define NWAVE 3125          // NN/16 exact
#define NBLK 782            // fused blocks (4 waves x 16 rows)
#define BS 48               // slots per node; P(deg>=47|Poisson(12)) ~ 5e-13
#define NB 196              // coarse buckets (dst>>8), 256 nodes each
#define PCAP 4608           // pairs per coarse bucket: mean 3061, sigma 55 -> 28-sigma margin
#define FA 147              // pass-A blocks: ceil(NE/4096)
#define WB1 16              // W1-pack blocks: 16384/1024
#define XB4 782             // x-convert blocks: ceil(800000/1024)
#define NREP 8              // stats replicas (atomic de-contention)

typedef __attribute__((ext_vector_type(8))) short short8;
typedef __attribute__((ext_vector_type(4))) float f32x4;

static __device__ __forceinline__ unsigned short f2bf(float f) {
  unsigned int u = __float_as_uint(f);
  unsigned int r = (u + 0x7FFFu + ((u >> 16) & 1u)) >> 16;   // RNE
  return (unsigned short)r;
}

// ------------------------------------------------ k_prep: edge binning + W1 pack + C/KB + x->bf16
//  [0,FA)            : bin edges into 196 coarse buckets
//  [FA,FA+WB1)       : pack W1 into MFMA B-fragment layout
//  [FA+WB1]          : C = W2@Wl (128x2), KB = b2@Wl + bl  (head collapse: gemm2 is linear)
//  [FA+WB1+1, ...)   : convert x -> bf16 (row-major)
__global__ __launch_bounds__(256) void k_prep(const float* __restrict__ x,
                                              const float* __restrict__ W1,
                                              const float* __restrict__ W2,
                                              const float* __restrict__ Wl,
                                              const float* __restrict__ b2,
                                              const float* __restrict__ bl,
                                              const int* __restrict__ ei,
                                              unsigned short* __restrict__ xb,
                                              unsigned short* __restrict__ W1p,
                                              float* __restrict__ Cf,
                                              float* __restrict__ KBf,
                                              int* __restrict__ gcnt,
                                              unsigned* __restrict__ pairs) {
  __shared__ int histA[NB], baseA[NB], curA[NB];
  int blk = blockIdx.x, t = threadIdx.x;
  if (blk < FA) {                                  // pass A: bin 4096 edges
    if (t < NB) histA[t] = 0;
    __syncthreads();
    int e0 = blk * 4096 + t;
#pragma unroll
    for (int i = 0; i < 16; ++i) {
      int e = e0 + i * 256;
      if (e < NE) atomicAdd(&histA[ei[NE + e] >> 8], 1);
    }
    __syncthreads();
    if (t < NB) {
      int h = histA[t];
      baseA[t] = h ? atomicAdd(&gcnt[t], h) : 0;
      curA[t] = 0;
    }
    __syncthreads();
#pragma unroll
    for (int i = 0; i < 16; ++i) {
      int e = e0 + i * 256;
      if (e < NE) {
        int s = ei[e];
        int d = ei[NE + e];
        int b = d >> 8;
        int p = baseA[b] + atomicAdd(&curA[b], 1);
        if (p < PCAP) pairs[b * PCAP + p] = (unsigned)s | ((unsigned)(d & 255) << 16);
      }
    }
    return;
  }
  blk -= FA;
  if (blk < WB1) {                                 // pack W1: 4 items/thread
    int base = blk * 1024 + t;
#pragma unroll
    for (int i = 0; i < 4; ++i) {
      int rem = base + i * 256;                    // 0..16383
      int ks = rem >> 12;
      int nf = (rem >> 9) & 7;
      int l  = (rem >> 3) & 63;
      int j  = rem & 7;
      int k = ks * 32 + (l >> 4) * 8 + j;
      int n = nf * 16 + (l & 15);
      W1p[rem] = f2bf(W1[k * D + n]);
    }
    return;
  }
  blk -= WB1;
  if (blk == 0) {                                  // C = W2@Wl (fp32), KB = b2@Wl + bl
    {
      int k = t >> 1, c = t & 1;                   // 256 threads -> 128x2
      const float4* w2r = (const float4*)(W2 + k * D);
      float s = 0.f;
#pragma unroll
      for (int m4 = 0; m4 < 32; ++m4) {
        float4 wv = w2r[m4];
        int m = m4 * 4;
        s += wv.x * Wl[(m + 0) * 2 + c] + wv.y * Wl[(m + 1) * 2 + c] +
             wv.z * Wl[(m + 2) * 2 + c] + wv.w * Wl[(m + 3) * 2 + c];
      }
      Cf[k * 2 + c] = s;
    }
    if (t < 2) {
      float s = bl[t];
      for (int m = 0; m < D; ++m) s += b2[m] * Wl[m * 2 + t];
      KBf[t] = s;
    }
    return;
  }
  blk -= 1;
  {                                                // convert x: 4 uint4/thread
    int64_t base = (int64_t)blk * 1024 + t;
    const float4* xs = (const float4*)x;
#pragma unroll
    for (int i = 0; i < 4; ++i) {
      int64_t idx = base + i * 256;
      if (idx < (int64_t)NN * D / 8) {
        float4 f0 = xs[idx * 2], f1 = xs[idx * 2 + 1];
        uint4 o;
        o.x = (unsigned)f2bf(f0.x) | ((unsigned)f2bf(f0.y) << 16);
        o.y = (unsigned)f2bf(f0.z) | ((unsigned)f2bf(f0.w) << 16);
        o.z = (unsigned)f2bf(f1.x) | ((unsigned)f2bf(f1.y) << 16);
        o.w = (unsigned)f2bf(f1.z) | ((unsigned)f2bf(f1.w) << 16);
        ((uint4*)xb)[idx] = o;
      }
    }
  }
}

// ------------------------------------------------ k_fill2: per-bucket LDS CSR build + coalesced flush
__global__ __launch_bounds__(256) void k_fill2(const unsigned* __restrict__ pairs,
                                               const int* __restrict__ gcnt,
                                               unsigned short* __restrict__ colw,
                                               int* __restrict__ cursor) {
  __shared__ unsigned short cs[256 * BS];          // 24576 B
  __shared__ int cur[256];
  int b = blockIdx.x, t = threadIdx.x;
  cur[t] = 0;
  __syncthreads();
  int cnt = gcnt[b]; if (cnt > PCAP) cnt = PCAP;
  for (int i = t; i < cnt; i += 256) {
    unsigned u = pairs[b * PCAP + i];
    int dl = (u >> 16) & 255;
    int pos = atomicAdd(&cur[dl], 1);
    if (pos < BS) cs[dl * BS + pos] = (unsigned short)(u & 0xFFFFu);
  }
  __syncthreads();
  uint4* dst = (uint4*)(colw + (size_t)b * 256 * BS);   // 24576 B / 16 = 1536 uint4
  const uint4* src = (const uint4*)cs;
  for (int i = t; i < 1536; i += 256) dst[i] = src[i];
  cursor[b * 256 + t] = (cur[t] < BS) ? cur[t] : BS;
}

// ------------------------------------------------ k_fusedA: gather (-> LDS tile) -> gemm1 -> h1b + stats
// 782 blocks x 256 threads, 64 nodes/block (16/wave). R2-verified structure.
// Gather: one node per 16-lane group, 8 rows in flight per lane (ILP 4->8);
// self-term folded into the prefetched index regs (select-before-load masking).
// h0 lands in an XOR-swizzled LDS tile; gemm1 reads A-frags from the tile,
// writes h1 (bf16, pre-BN) to global; BN stats -> REPLICATED global atomics
// (stats[blockIdx&7][256]) to break cross-XCD same-line serialization.
__global__ __launch_bounds__(256) void k_fusedA(const unsigned short* __restrict__ xb,
                                                const int* __restrict__ cursor,
                                                const unsigned short* __restrict__ colw,
                                                const unsigned short* __restrict__ W1p,
                                                const float* __restrict__ b1,
                                                unsigned short* __restrict__ h1b,
                                                float* __restrict__ stats) {
  __shared__ uint4 tile[64 * 16];                  // 16 KB: 64 rows x 128 bf16, swizzled
  __shared__ float redS[D], redQ[D];
  int t = threadIdx.x;
  if (t < D) { redS[t] = 0.f; redQ[t] = 0.f; }
  __syncthreads();

  int w = t >> 6, lane = t & 63;
  int g = lane >> 4, l = lane & 15;
  int wave_id = blockIdx.x * 4 + w;
  bool valid = wave_id < NWAVE;
  int row0 = wave_id * 16;
  const uint4* xv = (const uint4*)xb;

  if (valid) {
    // ---------- phase 1: gather 16 nodes (4 sub-rounds x 4 nodes, one node per group)
    int curAll = (lane < 16) ? cursor[row0 + lane] : 0;
#define GSRC(k) __shfl(((k) < 16 ? cl0 : ((k) < 32 ? cl1 : cl2)), (g << 4) + ((k) & 15))
#define MSK(v, kk) { unsigned m_ = ((kk) < dcap) ? 0xFFFFFFFFu : 0u; \
                     (v).x &= m_; (v).y &= m_; (v).z &= m_; (v).w &= m_; }
#define ACC8(v)                                     \
  { a0 += __uint_as_float((v).x << 16);             \
    a1 += __uint_as_float((v).x & 0xFFFF0000u);     \
    a2 += __uint_as_float((v).y << 16);             \
    a3 += __uint_as_float((v).y & 0xFFFF0000u);     \
    a4 += __uint_as_float((v).z << 16);             \
    a5 += __uint_as_float((v).z & 0xFFFF0000u);     \
    a6 += __uint_as_float((v).w << 16);             \
    a7 += __uint_as_float((v).w & 0xFFFF0000u); }
    for (int sub = 0; sub < 4; ++sub) {
      int node = row0 + sub * 4 + g;
      int ec = __shfl(curAll, sub * 4 + g);        // edge count (<= BS from k_fill2)
      if (ec > BS - 1) ec = BS - 1;                // reserve one slot for self
      int dcap = ec + 1;                           // slots incl. self
      int cbase = node * BS;
      int cl0 = (l < ec) ? (int)colw[cbase + l]
                         : ((l == ec) ? node : 0);           // self folded in
      int cl1 = (l + 16 < ec) ? (int)colw[cbase + 16 + l]
                              : ((l + 16 == ec) ? node : 0);
      int cl2 = (l + 32 < ec) ? (int)colw[cbase + 32 + l]
                              : ((l + 32 == ec) ? node : 0);
      int maxd = dcap;
      maxd = max(maxd, __shfl_xor(maxd, 16));
      maxd = max(maxd, __shfl_xor(maxd, 32));      // wave-uniform trip bound
      float a0 = 0, a1 = 0, a2 = 0, a3 = 0, a4 = 0, a5 = 0, a6 = 0, a7 = 0;
      int nit = (maxd + 7) >> 3;                   // 8 slots per iteration
      for (int it = 0; it < nit; ++it) {
        int k0 = it << 3;
        int i0 = GSRC(k0);
        int i1 = GSRC(k0 + 1);
        int i2 = GSRC(k0 + 2);
        int i3 = GSRC(k0 + 3);
        int i4 = GSRC(k0 + 4);
        int i5 = GSRC(k0 + 5);
        int i6 = GSRC(k0 + 6);
        int i7 = GSRC(k0 + 7);
        uint4 v0 = xv[(unsigned)i0 * 16u + l];     // 8 rows in flight / lane
        uint4 v1 = xv[(unsigned)i1 * 16u + l];
        uint4 v2 = xv[(unsigned)i2 * 16u + l];
        uint4 v3 = xv[(unsigned)i3 * 16u + l];
        uint4 v4 = xv[(unsigned)i4 * 16u + l];
        uint4 v5 = xv[(unsigned)i5 * 16u + l];
        uint4 v6 = xv[(unsigned)i6 * 16u + l];
        uint4 v7 = xv[(unsigned)i7 * 16u + l];
        MSK(v0, k0) MSK(v1, k0 + 1) MSK(v2, k0 + 2) MSK(v3, k0 + 3)
        MSK(v4, k0 + 4) MSK(v5, k0 + 5) MSK(v6, k0 + 6) MSK(v7, k0 + 7)
        ACC8(v0) ACC8(v1) ACC8(v2) ACC8(v3)
        ACC8(v4) ACC8(v5) ACC8(v6) ACC8(v7)
      }
      uint4 o;
      o.x = (unsigned)f2bf(a0) | ((unsigned)f2bf(a1) << 16);
      o.y = (unsigned)f2bf(a2) | ((unsigned)f2bf(a3) << 16);
      o.z = (unsigned)f2bf(a4) | ((unsigned)f2bf(a5) << 16);
      o.w = (unsigned)f2bf(a6) | ((unsigned)f2bf(a7) << 16);
      int rb = (w << 4) + (sub << 2) + g;          // block-local row
      tile[(rb * 16 + l) ^ (rb & 7)] = o;          // swizzled store (conflict-free)
    }
#undef GSRC
#undef MSK
#undef ACC8

    // ---------- phase 2: gemm1 (h0 from LDS -> relu(h0@W1+b1) -> h1b + stats)
    {
      int rb = (w << 4) + l;
      short8 a[4];
#pragma unroll
      for (int ks = 0; ks < 4; ++ks)
        a[ks] = *(const short8*)&tile[(rb * 16 + ks * 4 + g) ^ (rb & 7)];

      f32x4 acc[8];
#pragma unroll
      for (int nf = 0; nf < 8; ++nf) { f32x4 z = {0.f, 0.f, 0.f, 0.f}; acc[nf] = z; }

      const short8* B = (const short8*)W1p;
#pragma unroll
      for (int ks = 0; ks < 4; ++ks)
#pragma unroll
        for (int nf = 0; nf < 8; ++nf)
          acc[nf] = __builtin_amdgcn_mfma_f32_16x16x32_bf16(a[ks], B[(ks * 8 + nf) * 64 + lane],
                                                            acc[nf], 0, 0, 0);

#pragma unroll
      for (int nf = 0; nf < 8; ++nf) {
        int colc = nf * 16 + l;
        float bias = b1[colc];
        float ps = 0.f, pq = 0.f;
#pragma unroll
        for (int r = 0; r < 4; ++r) {
          float v = fmaxf(acc[nf][r] + bias, 0.f);
          int row = row0 + g * 4 + r;
          h1b[(int64_t)row * D + colc] = f2bf(v);
          ps += v; pq += v * v;
        }
        ps += __shfl_xor(ps, 16); ps += __shfl_xor(ps, 32);
        pq += __shfl_xor(pq, 16); pq += __shfl_xor(pq, 32);
        if (g == 0) { atomicAdd(&redS[colc], ps); atomicAdd(&redQ[colc], pq); }
      }
    }
  }
  __syncthreads();
  {
    int r = blockIdx.x & (NREP - 1);               // replicated stats: 8x less line contention
    if (t < D) {
      unsafeAtomicAdd(&stats[r * 256 + t], redS[t]);
      unsafeAtomicAdd(&stats[r * 256 + D + t], redQ[t]);
    }
  }
}

// ------------------------------------------------ k_head: BN-fold + collapsed linear head (fp32)
// logits = BN(h1) @ C + KB,  C = W2@Wl (128x2), KB = b2@Wl + bl.
__global__ __launch_bounds__(256) void k_head(const unsigned short* __restrict__ h1b,
                                              const float* __restrict__ stats,
                                              const float* __restrict__ gamma,
                                              const float* __restrict__ beta,
                                              const float* __restrict__ Cf,
                                              const float* __restrict__ KBf,
                                              float* __restrict__ out) {
  __shared__ float sc_s[D], sh_s[D];
  __shared__ float2 c2_s[D];
  int t = threadIdx.x;
  if (t < D) {
    float s = 0.f, q = 0.f;
#pragma unroll
    for (int r = 0; r < NREP; ++r) {               // sum the 8 replicas
      s += stats[r * 256 + t];
      q += stats[r * 256 + D + t];
    }
    const float inv_n = 1.0f / (float)NN;
    float mean = s * inv_n;
    float var = q * inv_n - mean * mean;
    float sc = gamma[t] * rsqrtf(var + 1e-5f);
    sc_s[t] = sc;
    sh_s[t] = beta[t] - mean * sc;
    c2_s[t] = ((const float2*)Cf)[t];
  }
  __syncthreads();
  int node = blockIdx.x * 16 + (t >> 4);           // 3125 blocks * 16 = NN exact
  int l = t & 15;
  uint4 v = ((const uint4*)h1b)[node * 16 + l];
  int k0 = l * 8;
  float e0 = __uint_as_float(v.x << 16), e1 = __uint_as_float(v.x & 0xFFFF0000u);
  float e2 = __uint_as_float(v.y << 16), e3 = __uint_as_float(v.y & 0xFFFF0000u);
  float e4 = __uint_as_float(v.z << 16), e5 = __uint_as_float(v.z & 0xFFFF0000u);
  float e6 = __uint_as_float(v.w << 16), e7 = __uint_as_float(v.w & 0xFFFF0000u);
  float p0 = 0.f, p1 = 0.f;
#define HC(ej, jj) { float u_ = ej * sc_s[k0 + jj] + sh_s[k0 + jj];  \
                     float2 c_ = c2_s[k0 + jj];                      \
                     p0 += u_ * c_.x; p1 += u_ * c_.y; }
  HC(e0, 0) HC(e1, 1) HC(e2, 2) HC(e3, 3) HC(e4, 4) HC(e5, 5) HC(e6, 6) HC(e7, 7)
#undef HC
  p0 += __shfl_xor(p0, 1); p0 += __shfl_xor(p0, 2);
  p0 += __shfl_xor(p0, 4); p0 += __shfl_xor(p0, 8);
  p1 += __shfl_xor(p1, 1); p1 += __shfl_xor(p1, 2);
  p1 += __shfl_xor(p1, 4); p1 += __shfl_xor(p1, 8);
  if (l == 0) {
    float2 kb = ((const float2*)KBf)[0];
    ((float2*)out)[node] = make_float2(p0 + kb.x, p1 + kb.y);
  }
}

// ------------------------------------------------ launcher
extern "C" void kernel_launch(void* const* d_in, const int* in_sizes, int n_in,
                              void* d_out, int out_size, void* d_ws, size_t ws_size,
                              hipStream_t stream) {
  const float* x     = (const float*)d_in[0];
  const int*   ei    = (const int*)d_in[1];
  const float* W1    = (const float*)d_in[2];
  const float* b1    = (const float*)d_in[3];
  const float* gamma = (const float*)d_in[4];
  const float* beta  = (const float*)d_in[5];
  const float* W2    = (const float*)d_in[6];
  const float* b2    = (const float*)d_in[7];
  const float* Wl    = (const float*)d_in[8];
  const float* bl    = (const float*)d_in[9];
  float* out = (float*)d_out;

  // workspace layout (~34 MB)
  unsigned short* xb  = (unsigned short*)d_ws;            // NN*D
  unsigned short* h1b = xb + (int64_t)NN * D;             // NN*D
  unsigned short* W1p = h1b + (int64_t)NN * D;            // 16384
  float* Cf     = (float*)(W1p + 16384);                  // 256 floats (C = W2@Wl as float2[128])
  float* KBf    = Cf + 256;                               // 4 floats (2 used)
  float* stats  = KBf + 4;                                // NREP*256 floats (replicated S|Q)
  int* gcnt     = (int*)(stats + NREP * 256);             // 256 ints (contiguous: one memset)
  int* cursor   = gcnt + 256;                             // NPAD (fully written by k_fill2)
  unsigned* pairs = (unsigned*)(cursor + NPAD);           // NB*PCAP
  unsigned short* colw = (unsigned short*)(pairs + (size_t)NB * PCAP);  // NPAD*BS

  hipMemsetAsync(stats, 0, (NREP * 256 + 256) * sizeof(float), stream);  // stats + gcnt
  k_prep<<<FA + WB1 + 1 + XB4, 256, 0, stream>>>(x, W1, W2, Wl, b2, bl, ei,
                                                 xb, W1p, Cf, KBf, gcnt, pairs);
  k_fill2<<<NB, 256, 0, stream>>>(pairs, gcnt, colw, cursor);
  k_fusedA<<<NBLK, 256, 0, stream>>>(xb, cursor, colw, W1p, b1, h1b, stats);
  k_head<<<NN / 16, 256, 0, stream>>>(h1b, stats, gamma, beta, Cf, KBf, out);
}

// Round 7
// 73.327 us; speedup vs baseline: 1.6444x; 1.0255x over previous
//
#include <hip/hip_runtime.h>
#include <cstdint>

#define NN 50000
#define NE 600000
#define D 128
#define NWAVE 3125          // NN/16 exact
#define NBLK 782            // fused blocks (4 waves x 16 rows = 64 nodes)
#define BS 48               // slots per node; P(deg>=47|Poisson(12)) ~ 5e-13
#define NB 196              // coarse buckets (dst>>8), 256 nodes each
#define PCAP 4608           // pairs per coarse bucket: mean 3061, sigma 55 -> 28-sigma margin
#define FA 147              // pass-A blocks: ceil(NE/4096)
#define WB1 16              // W1-pack blocks: 16384/1024
#define XB4 782             // x-convert blocks: ceil(800000/1024)
#define NREP 16             // stats replicas (atomic de-contention)

typedef __attribute__((ext_vector_type(8))) short short8;
typedef __attribute__((ext_vector_type(4))) float f32x4;

static __device__ __forceinline__ unsigned short f2bf(float f) {
  unsigned int u = __float_as_uint(f);
  unsigned int r = (u + 0x7FFFu + ((u >> 16) & 1u)) >> 16;   // RNE
  return (unsigned short)r;
}

// ------------------------------------------------ k_prep: edge binning + W1 pack + C/KB + x->bf16
//  [0,FA)            : bin edges into 196 coarse buckets
//  [FA,FA+WB1)       : pack W1 into MFMA B-fragment layout
//  [FA+WB1]          : C = W2@Wl (128x2), KB = b2@Wl + bl  (head collapse: gemm2 is linear)
//  [FA+WB1+1, ...)   : convert x -> bf16 (row-major)
__global__ __launch_bounds__(256) void k_prep(const float* __restrict__ x,
                                              const float* __restrict__ W1,
                                              const float* __restrict__ W2,
                                              const float* __restrict__ Wl,
                                              const float* __restrict__ b2,
                                              const float* __restrict__ bl,
                                              const int* __restrict__ ei,
                                              unsigned short* __restrict__ xb,
                                              unsigned short* __restrict__ W1p,
                                              float* __restrict__ Cf,
                                              float* __restrict__ KBf,
                                              int* __restrict__ gcnt,
                                              unsigned* __restrict__ pairs) {
  __shared__ int histA[NB], baseA[NB], curA[NB];
  int blk = blockIdx.x, t = threadIdx.x;
  if (blk < FA) {                                  // pass A: bin 4096 edges
    if (t < NB) histA[t] = 0;
    __syncthreads();
    int e0 = blk * 4096 + t;
#pragma unroll
    for (int i = 0; i < 16; ++i) {
      int e = e0 + i * 256;
      if (e < NE) atomicAdd(&histA[ei[NE + e] >> 8], 1);
    }
    __syncthreads();
    if (t < NB) {
      int h = histA[t];
      baseA[t] = h ? atomicAdd(&gcnt[t], h) : 0;
      curA[t] = 0;
    }
    __syncthreads();
#pragma unroll
    for (int i = 0; i < 16; ++i) {
      int e = e0 + i * 256;
      if (e < NE) {
        int s = ei[e];
        int d = ei[NE + e];
        int b = d >> 8;
        int p = baseA[b] + atomicAdd(&curA[b], 1);
        if (p < PCAP) pairs[b * PCAP + p] = (unsigned)s | ((unsigned)(d & 255) << 16);
      }
    }
    return;
  }
  blk -= FA;
  if (blk < WB1) {                                 // pack W1: 4 items/thread
    int base = blk * 1024 + t;
#pragma unroll
    for (int i = 0; i < 4; ++i) {
      int rem = base + i * 256;                    // 0..16383
      int ks = rem >> 12;
      int nf = (rem >> 9) & 7;
      int l  = (rem >> 3) & 63;
      int j  = rem & 7;
      int k = ks * 32 + (l >> 4) * 8 + j;
      int n = nf * 16 + (l & 15);
      W1p[rem] = f2bf(W1[k * D + n]);
    }
    return;
  }
  blk -= WB1;
  if (blk == 0) {                                  // C = W2@Wl (fp32), KB = b2@Wl + bl
    {
      int k = t >> 1, c = t & 1;                   // 256 threads -> 128x2
      const float4* w2r = (const float4*)(W2 + k * D);
      float s = 0.f;
#pragma unroll
      for (int m4 = 0; m4 < 32; ++m4) {
        float4 wv = w2r[m4];
        int m = m4 * 4;
        s += wv.x * Wl[(m + 0) * 2 + c] + wv.y * Wl[(m + 1) * 2 + c] +
             wv.z * Wl[(m + 2) * 2 + c] + wv.w * Wl[(m + 3) * 2 + c];
      }
      Cf[k * 2 + c] = s;
    }
    if (t < 2) {
      float s = bl[t];
      for (int m = 0; m < D; ++m) s += b2[m] * Wl[m * 2 + t];
      KBf[t] = s;
    }
    return;
  }
  blk -= 1;
  {                                                // convert x: 4 uint4/thread
    int64_t base = (int64_t)blk * 1024 + t;
    const float4* xs = (const float4*)x;
#pragma unroll
    for (int i = 0; i < 4; ++i) {
      int64_t idx = base + i * 256;
      if (idx < (int64_t)NN * D / 8) {
        float4 f0 = xs[idx * 2], f1 = xs[idx * 2 + 1];
        uint4 o;
        o.x = (unsigned)f2bf(f0.x) | ((unsigned)f2bf(f0.y) << 16);
        o.y = (unsigned)f2bf(f0.z) | ((unsigned)f2bf(f0.w) << 16);
        o.z = (unsigned)f2bf(f1.x) | ((unsigned)f2bf(f1.y) << 16);
        o.w = (unsigned)f2bf(f1.z) | ((unsigned)f2bf(f1.w) << 16);
        ((uint4*)xb)[idx] = o;
      }
    }
  }
}

// ------------------------------------------------ k_fusedA: CSR-in-LDS -> gather (-> LDS tile) -> gemm1
// 782 blocks x 256 threads, 64 nodes/block (16/wave). R6-verified core.
// Phase 0 (NEW): build this block's 64-node CSR in LDS directly from the coarse
// bucket (block f scans bucket f>>2, keeps quarter f&3) — k_fill2 dispatch and
// the colw global round-trip are gone.
// Phase 1: one node per 16-lane group, 8 rows in flight per lane; self-term
// folded into the index regs (select-before-load). h0 -> XOR-swizzled LDS tile.
// Phase 2: MFMA gemm1 from tile; h1 (bf16, pre-BN) -> global; BN stats ->
// replicated global atomics (stats[blockIdx&15][256]).
__global__ __launch_bounds__(256) void k_fusedA(const unsigned short* __restrict__ xb,
                                                const int* __restrict__ gcnt,
                                                const unsigned* __restrict__ pairs,
                                                const unsigned short* __restrict__ W1p,
                                                const float* __restrict__ b1,
                                                unsigned short* __restrict__ h1b,
                                                float* __restrict__ stats) {
  __shared__ uint4 tile[64 * 16];                  // 16 KB: 64 rows x 128 bf16, swizzled
  __shared__ unsigned short cs[64 * BS];           // 6 KB adjacency
  __shared__ int cur[64];
  __shared__ float redS[D], redQ[D];
  int t = threadIdx.x;
  if (t < D) { redS[t] = 0.f; redQ[t] = 0.f; }
  if (t < 64) cur[t] = 0;
  __syncthreads();

  // ---------- phase 0: CSR build from coarse bucket (quarter filter)
  {
    int bkt = blockIdx.x >> 2, qt = blockIdx.x & 3;
    int cnt = gcnt[bkt]; if (cnt > PCAP) cnt = PCAP;
    for (int i = t; i < cnt; i += 256) {
      unsigned u = pairs[bkt * PCAP + i];
      int dloc = (u >> 16) & 255;
      if ((dloc >> 6) == qt) {
        int dl = dloc & 63;
        int pos = atomicAdd(&cur[dl], 1);
        if (pos < BS - 1) cs[dl * BS + pos] = (unsigned short)(u & 0xFFFFu);  // slot BS-1 for self
      }
    }
  }
  __syncthreads();

  int w = t >> 6, lane = t & 63;
  int g = lane >> 4, l = lane & 15;
  int wave_id = blockIdx.x * 4 + w;
  bool valid = wave_id < NWAVE;
  int row0 = wave_id * 16;
  const uint4* xv = (const uint4*)xb;

  if (valid) {
    // ---------- phase 1: gather 16 nodes (4 sub-rounds x 4 nodes, one node per group)
#define GSRC(k) __shfl(((k) < 16 ? cl0 : ((k) < 32 ? cl1 : cl2)), (g << 4) + ((k) & 15))
#define MSK(v, kk) { unsigned m_ = ((kk) < dcap) ? 0xFFFFFFFFu : 0u; \
                     (v).x &= m_; (v).y &= m_; (v).z &= m_; (v).w &= m_; }
#define ACC8(v)                                     \
  { a0 += __uint_as_float((v).x << 16);             \
    a1 += __uint_as_float((v).x & 0xFFFF0000u);     \
    a2 += __uint_as_float((v).y << 16);             \
    a3 += __uint_as_float((v).y & 0xFFFF0000u);     \
    a4 += __uint_as_float((v).z << 16);             \
    a5 += __uint_as_float((v).z & 0xFFFF0000u);     \
    a6 += __uint_as_float((v).w << 16);             \
    a7 += __uint_as_float((v).w & 0xFFFF0000u); }
    for (int sub = 0; sub < 4; ++sub) {
      int dl = (w << 4) + (sub << 2) + g;          // block-local row 0..63
      int node = blockIdx.x * 64 + dl;
      int ec = cur[dl];                            // edge count (LDS broadcast)
      if (ec > BS - 1) ec = BS - 1;                // reserve one slot for self
      int dcap = ec + 1;                           // slots incl. self
      int cbase = dl * BS;
      int cl0 = (l < ec) ? (int)cs[cbase + l]
                         : ((l == ec) ? node : 0);           // self folded in
      int cl1 = (l + 16 < ec) ? (int)cs[cbase + 16 + l]
                              : ((l + 16 == ec) ? node : 0);
      int cl2 = (l + 32 < ec) ? (int)cs[cbase + 32 + l]
                              : ((l + 32 == ec) ? node : 0);
      int maxd = dcap;
      maxd = max(maxd, __shfl_xor(maxd, 16));
      maxd = max(maxd, __shfl_xor(maxd, 32));      // wave-uniform trip bound
      float a0 = 0, a1 = 0, a2 = 0, a3 = 0, a4 = 0, a5 = 0, a6 = 0, a7 = 0;
      int nit = (maxd + 7) >> 3;                   // 8 slots per iteration
      for (int it = 0; it < nit; ++it) {
        int k0 = it << 3;
        int i0 = GSRC(k0);
        int i1 = GSRC(k0 + 1);
        int i2 = GSRC(k0 + 2);
        int i3 = GSRC(k0 + 3);
        int i4 = GSRC(k0 + 4);
        int i5 = GSRC(k0 + 5);
        int i6 = GSRC(k0 + 6);
        int i7 = GSRC(k0 + 7);
        uint4 v0 = xv[(unsigned)i0 * 16u + l];     // 8 rows in flight / lane
        uint4 v1 = xv[(unsigned)i1 * 16u + l];
        uint4 v2 = xv[(unsigned)i2 * 16u + l];
        uint4 v3 = xv[(unsigned)i3 * 16u + l];
        uint4 v4 = xv[(unsigned)i4 * 16u + l];
        uint4 v5 = xv[(unsigned)i5 * 16u + l];
        uint4 v6 = xv[(unsigned)i6 * 16u + l];
        uint4 v7 = xv[(unsigned)i7 * 16u + l];
        MSK(v0, k0) MSK(v1, k0 + 1) MSK(v2, k0 + 2) MSK(v3, k0 + 3)
        MSK(v4, k0 + 4) MSK(v5, k0 + 5) MSK(v6, k0 + 6) MSK(v7, k0 + 7)
        ACC8(v0) ACC8(v1) ACC8(v2) ACC8(v3)
        ACC8(v4) ACC8(v5) ACC8(v6) ACC8(v7)
      }
      uint4 o;
      o.x = (unsigned)f2bf(a0) | ((unsigned)f2bf(a1) << 16);
      o.y = (unsigned)f2bf(a2) | ((unsigned)f2bf(a3) << 16);
      o.z = (unsigned)f2bf(a4) | ((unsigned)f2bf(a5) << 16);
      o.w = (unsigned)f2bf(a6) | ((unsigned)f2bf(a7) << 16);
      tile[(dl * 16 + l) ^ (dl & 7)] = o;          // swizzled store (conflict-free)
    }
#undef GSRC
#undef MSK
#undef ACC8

    // ---------- phase 2: gemm1 (h0 from LDS -> relu(h0@W1+b1) -> h1b + stats)
    {
      int rb = (w << 4) + l;
      short8 a[4];
#pragma unroll
      for (int ks = 0; ks < 4; ++ks)
        a[ks] = *(const short8*)&tile[(rb * 16 + ks * 4 + g) ^ (rb & 7)];

      f32x4 acc[8];
#pragma unroll
      for (int nf = 0; nf < 8; ++nf) { f32x4 z = {0.f, 0.f, 0.f, 0.f}; acc[nf] = z; }

      const short8* B = (const short8*)W1p;
#pragma unroll
      for (int ks = 0; ks < 4; ++ks)
#pragma unroll
        for (int nf = 0; nf < 8; ++nf)
          acc[nf] = __builtin_amdgcn_mfma_f32_16x16x32_bf16(a[ks], B[(ks * 8 + nf) * 64 + lane],
                                                            acc[nf], 0, 0, 0);

#pragma unroll
      for (int nf = 0; nf < 8; ++nf) {
        int colc = nf * 16 + l;
        float bias = b1[colc];
        float ps = 0.f, pq = 0.f;
#pragma unroll
        for (int r = 0; r < 4; ++r) {
          float v = fmaxf(acc[nf][r] + bias, 0.f);
          int row = row0 + g * 4 + r;
          h1b[(int64_t)row * D + colc] = f2bf(v);
          ps += v; pq += v * v;
        }
        ps += __shfl_xor(ps, 16); ps += __shfl_xor(ps, 32);
        pq += __shfl_xor(pq, 16); pq += __shfl_xor(pq, 32);
        if (g == 0) { atomicAdd(&redS[colc], ps); atomicAdd(&redQ[colc], pq); }
      }
    }
  }
  __syncthreads();
  {
    int r = blockIdx.x & (NREP - 1);               // replicated stats: 16x less line contention
    if (t < D) {
      unsafeAtomicAdd(&stats[r * 256 + t], redS[t]);
      unsafeAtomicAdd(&stats[r * 256 + D + t], redQ[t]);
    }
  }
}

// ------------------------------------------------ k_head: BN-fold + collapsed linear head (fp32)
// logits = BN(h1) @ C + KB,  C = W2@Wl (128x2), KB = b2@Wl + bl.
// Grid matches k_fusedA (782 blocks x 64 nodes) so each block reads h1b rows
// from the SAME XCD's L2 that wrote them (same round-robin block->XCD map).
__global__ __launch_bounds__(256) void k_head(const unsigned short* __restrict__ h1b,
                                              const float* __restrict__ stats,
                                              const float* __restrict__ gamma,
                                              const float* __restrict__ beta,
                                              const float* __restrict__ Cf,
                                              const float* __restrict__ KBf,
                                              float* __restrict__ out) {
  __shared__ float sc_s[D], sh_s[D];
  __shared__ float2 c2_s[D];
  int t = threadIdx.x;
  if (t < D) {
    float s = 0.f, q = 0.f;
#pragma unroll
    for (int r = 0; r < NREP; ++r) {               // sum the 16 replicas
      s += stats[r * 256 + t];
      q += stats[r * 256 + D + t];
    }
    const float inv_n = 1.0f / (float)NN;
    float mean = s * inv_n;
    float var = q * inv_n - mean * mean;
    float sc = gamma[t] * rsqrtf(var + 1e-5f);
    sc_s[t] = sc;
    sh_s[t] = beta[t] - mean * sc;
    c2_s[t] = ((const float2*)Cf)[t];
  }
  __syncthreads();
  float2 kb = ((const float2*)KBf)[0];
  int l = t & 15;
  int k0 = l * 8;
#pragma unroll
  for (int rd = 0; rd < 4; ++rd) {
    int node = blockIdx.x * 64 + rd * 16 + (t >> 4);
    if (node < NN) {
      uint4 v = ((const uint4*)h1b)[(int64_t)node * 16 + l];
      float e0 = __uint_as_float(v.x << 16), e1 = __uint_as_float(v.x & 0xFFFF0000u);
      float e2 = __uint_as_float(v.y << 16), e3 = __uint_as_float(v.y & 0xFFFF0000u);
      float e4 = __uint_as_float(v.z << 16), e5 = __uint_as_float(v.z & 0xFFFF0000u);
      float e6 = __uint_as_float(v.w << 16), e7 = __uint_as_float(v.w & 0xFFFF0000u);
      float p0 = 0.f, p1 = 0.f;
#define HC(ej, jj) { float u_ = ej * sc_s[k0 + jj] + sh_s[k0 + jj];  \
                     float2 c_ = c2_s[k0 + jj];                      \
                     p0 += u_ * c_.x; p1 += u_ * c_.y; }
      HC(e0, 0) HC(e1, 1) HC(e2, 2) HC(e3, 3) HC(e4, 4) HC(e5, 5) HC(e6, 6) HC(e7, 7)
#undef HC
      p0 += __shfl_xor(p0, 1); p0 += __shfl_xor(p0, 2);
      p0 += __shfl_xor(p0, 4); p0 += __shfl_xor(p0, 8);
      p1 += __shfl_xor(p1, 1); p1 += __shfl_xor(p1, 2);
      p1 += __shfl_xor(p1, 4); p1 += __shfl_xor(p1, 8);
      if (l == 0) ((float2*)out)[node] = make_float2(p0 + kb.x, p1 + kb.y);
    }
  }
}

// ------------------------------------------------ launcher
extern "C" void kernel_launch(void* const* d_in, const int* in_sizes, int n_in,
                              void* d_out, int out_size, void* d_ws, size_t ws_size,
                              hipStream_t stream) {
  const float* x     = (const float*)d_in[0];
  const int*   ei    = (const int*)d_in[1];
  const float* W1    = (const float*)d_in[2];
  const float* b1    = (const float*)d_in[3];
  const float* gamma = (const float*)d_in[4];
  const float* beta  = (const float*)d_in[5];
  const float* W2    = (const float*)d_in[6];
  const float* b2    = (const float*)d_in[7];
  const float* Wl    = (const float*)d_in[8];
  const float* bl    = (const float*)d_in[9];
  float* out = (float*)d_out;

  // workspace layout (~30 MB)
  unsigned short* xb  = (unsigned short*)d_ws;            // NN*D
  unsigned short* h1b = xb + (int64_t)NN * D;             // NN*D
  unsigned short* W1p = h1b + (int64_t)NN * D;            // 16384
  float* Cf     = (float*)(W1p + 16384);                  // 256 floats (C = W2@Wl as float2[128])
  float* KBf    = Cf + 256;                               // 4 floats (2 used)
  float* stats  = KBf + 4;                                // NREP*256 floats (replicated S|Q)
  int* gcnt     = (int*)(stats + NREP * 256);             // 256 ints (contiguous: one memset)
  unsigned* pairs = (unsigned*)(gcnt + 256);              // NB*PCAP (~3.6 MB)

  hipMemsetAsync(stats, 0, (NREP * 256 + 256) * sizeof(float), stream);  // stats + gcnt
  k_prep<<<FA + WB1 + 1 + XB4, 256, 0, stream>>>(x, W1, W2, Wl, b2, bl, ei,
                                                 xb, W1p, Cf, KBf, gcnt, pairs);
  k_fusedA<<<NBLK, 256, 0, stream>>>(xb, gcnt, pairs, W1p, b1, h1b, stats);
  k_head<<<NBLK, 256, 0, stream>>>(h1b, stats, gamma, beta, Cf, KBf, out);
}

// Round 8
// 70.599 us; speedup vs baseline: 1.7080x; 1.0386x over previous
//
#include <hip/hip_runtime.h>
#include <cstdint>

#define NN 50000
#define NE 600000
#define D 128
#define BS 48               // slots per node (incl. self)
#define NB2 1563            // fine buckets (dst>>5), 32 nodes each
#define PCAP2 640           // pairs per bucket: mean 384, sigma 19.6 -> 13-sigma margin
#define FA 147              // pass-A blocks: ceil(NE/4096)
#define WB1 16              // W1-pack blocks: 16384/1024
#define XB4 782             // x-convert blocks: ceil(800000/1024)
#define NREP 16             // stats replicas (atomic de-contention)

typedef __attribute__((ext_vector_type(8))) short short8;
typedef __attribute__((ext_vector_type(4))) float f32x4;

static __device__ __forceinline__ unsigned short f2bf(float f) {
  unsigned int u = __float_as_uint(f);
  unsigned int r = (u + 0x7FFFu + ((u >> 16) & 1u)) >> 16;   // RNE
  return (unsigned short)r;
}

// ------------------------------------------------ k_prep: fine edge binning + W1 pack + C/KB + x->bf16
//  [0,FA)            : bin edges into 1563 fine buckets (32 dst nodes each); edges reg-cached
//  [FA,FA+WB1)       : pack W1 into MFMA B-fragment layout
//  [FA+WB1]          : C = W2@Wl (128x2), KB = b2@Wl + bl  (head collapse: gemm2 is linear)
//  [FA+WB1+1, ...)   : convert x -> bf16 (row-major)
__global__ __launch_bounds__(256) void k_prep(const float* __restrict__ x,
                                              const float* __restrict__ W1,
                                              const float* __restrict__ W2,
                                              const float* __restrict__ Wl,
                                              const float* __restrict__ b2,
                                              const float* __restrict__ bl,
                                              const int* __restrict__ ei,
                                              unsigned short* __restrict__ xb,
                                              unsigned short* __restrict__ W1p,
                                              float* __restrict__ Cf,
                                              float* __restrict__ KBf,
                                              int* __restrict__ gcnt,
                                              unsigned* __restrict__ pairs) {
  __shared__ int histA[NB2], baseA[NB2], curA[NB2];   // 18.3 KB
  int blk = blockIdx.x, t = threadIdx.x;
  if (blk < FA) {                                  // pass A: bin 4096 edges
    for (int i = t; i < NB2; i += 256) histA[i] = 0;
    __syncthreads();
    int e0 = blk * 4096 + t;
    int sreg[16], dreg[16];
#pragma unroll
    for (int i = 0; i < 16; ++i) {                 // single read of src+dst into regs
      int e = e0 + i * 256;
      bool ok = e < NE;
      sreg[i] = ok ? ei[e] : 0;
      dreg[i] = ok ? ei[NE + e] : -1;
      if (ok) atomicAdd(&histA[dreg[i] >> 5], 1);
    }
    __syncthreads();
    for (int i = t; i < NB2; i += 256) {
      int h = histA[i];
      baseA[i] = h ? atomicAdd(&gcnt[i], h) : 0;
      curA[i] = 0;
    }
    __syncthreads();
#pragma unroll
    for (int i = 0; i < 16; ++i) {
      if (dreg[i] >= 0) {
        int b = dreg[i] >> 5;
        int p = baseA[b] + atomicAdd(&curA[b], 1);
        if (p < PCAP2)
          pairs[b * PCAP2 + p] = (unsigned)sreg[i] | ((unsigned)(dreg[i] & 31) << 16);
      }
    }
    return;
  }
  blk -= FA;
  if (blk < WB1) {                                 // pack W1: 4 items/thread
    int base = blk * 1024 + t;
#pragma unroll
    for (int i = 0; i < 4; ++i) {
      int rem = base + i * 256;                    // 0..16383
      int ks = rem >> 12;
      int nf = (rem >> 9) & 7;
      int l  = (rem >> 3) & 63;
      int j  = rem & 7;
      int k = ks * 32 + (l >> 4) * 8 + j;
      int n = nf * 16 + (l & 15);
      W1p[rem] = f2bf(W1[k * D + n]);
    }
    return;
  }
  blk -= WB1;
  if (blk == 0) {                                  // C = W2@Wl (fp32), KB = b2@Wl + bl
    {
      int k = t >> 1, c = t & 1;                   // 256 threads -> 128x2
      const float4* w2r = (const float4*)(W2 + k * D);
      float s = 0.f;
#pragma unroll
      for (int m4 = 0; m4 < 32; ++m4) {
        float4 wv = w2r[m4];
        int m = m4 * 4;
        s += wv.x * Wl[(m + 0) * 2 + c] + wv.y * Wl[(m + 1) * 2 + c] +
             wv.z * Wl[(m + 2) * 2 + c] + wv.w * Wl[(m + 3) * 2 + c];
      }
      Cf[k * 2 + c] = s;
    }
    if (t < 2) {
      float s = bl[t];
      for (int m = 0; m < D; ++m) s += b2[m] * Wl[m * 2 + t];
      KBf[t] = s;
    }
    return;
  }
  blk -= 1;
  {                                                // convert x: 4 uint4/thread
    int64_t base = (int64_t)blk * 1024 + t;
    const float4* xs = (const float4*)x;
#pragma unroll
    for (int i = 0; i < 4; ++i) {
      int64_t idx = base + i * 256;
      if (idx < (int64_t)NN * D / 8) {
        float4 f0 = xs[idx * 2], f1 = xs[idx * 2 + 1];
        uint4 o;
        o.x = (unsigned)f2bf(f0.x) | ((unsigned)f2bf(f0.y) << 16);
        o.y = (unsigned)f2bf(f0.z) | ((unsigned)f2bf(f0.w) << 16);
        o.z = (unsigned)f2bf(f1.x) | ((unsigned)f2bf(f1.y) << 16);
        o.w = (unsigned)f2bf(f1.z) | ((unsigned)f2bf(f1.w) << 16);
        ((uint4*)xb)[idx] = o;
      }
    }
  }
}

// ------------------------------------------------ k_fusedA: CSR-in-LDS -> gather (-> LDS tile) -> gemm1
// 1563 blocks x 256 threads, 32 nodes/block (8/wave). 2x the resident waves/CU
// of the R6/R7 64-node variant (clean TLP A/B: R3's garbage-index + VGPR-squeeze
// confounds removed). Phase 0: CSR from OWN fine bucket (2.5 KB read).
// Phase 1: R6-verified gather core — one node per 16-lane group, 8 rows in
// flight/lane, self folded into index regs, select-before-load masking;
// h0 -> XOR-swizzled LDS tile. Phase 2 (cross-wave => barrier): MFMA gemm1,
// wave = (row-half th, nf-half nh); h1 -> global; stats -> replicated atomics.
__global__ __launch_bounds__(256) void k_fusedA(const unsigned short* __restrict__ xb,
                                                const int* __restrict__ gcnt,
                                                const unsigned* __restrict__ pairs,
                                                const unsigned short* __restrict__ W1p,
                                                const float* __restrict__ b1,
                                                unsigned short* __restrict__ h1b,
                                                float* __restrict__ stats) {
  __shared__ uint4 tile[32 * 16];                  // 8 KB: 32 rows x 128 bf16, swizzled
  __shared__ unsigned short cs[32 * BS];           // 3 KB adjacency
  __shared__ int cur[32];
  __shared__ float redS[D], redQ[D];
  int t = threadIdx.x, b = blockIdx.x;
  if (t < D) { redS[t] = 0.f; redQ[t] = 0.f; }
  if (t < 32) cur[t] = 0;
  __syncthreads();

  // ---------- phase 0: CSR build from this block's own fine bucket
  {
    int cnt = gcnt[b]; if (cnt > PCAP2) cnt = PCAP2;
    for (int i = t; i < cnt; i += 256) {
      unsigned u = pairs[b * PCAP2 + i];
      int dl = (u >> 16) & 31;
      int pos = atomicAdd(&cur[dl], 1);
      if (pos < BS - 1) cs[dl * BS + pos] = (unsigned short)(u & 0xFFFFu);  // slot BS-1 for self
    }
  }
  __syncthreads();

  int w = t >> 6, lane = t & 63;
  int g = lane >> 4, l = lane & 15;
  const uint4* xv = (const uint4*)xb;

  // ---------- phase 1: gather 8 nodes per wave (2 sub-rounds x 4 nodes)
#define GSRC(k) __shfl(((k) < 16 ? cl0 : ((k) < 32 ? cl1 : cl2)), (g << 4) + ((k) & 15))
#define MSK(v, kk) { unsigned m_ = ((kk) < dcap) ? 0xFFFFFFFFu : 0u; \
                     (v).x &= m_; (v).y &= m_; (v).z &= m_; (v).w &= m_; }
#define ACC8(v)                                     \
  { a0 += __uint_as_float((v).x << 16);             \
    a1 += __uint_as_float((v).x & 0xFFFF0000u);     \
    a2 += __uint_as_float((v).y << 16);             \
    a3 += __uint_as_float((v).y & 0xFFFF0000u);     \
    a4 += __uint_as_float((v).z << 16);             \
    a5 += __uint_as_float((v).z & 0xFFFF0000u);     \
    a6 += __uint_as_float((v).w << 16);             \
    a7 += __uint_as_float((v).w & 0xFFFF0000u); }
  for (int sub = 0; sub < 2; ++sub) {
    int dl = (w << 3) + (sub << 2) + g;            // block-local row 0..31
    int node = b * 32 + dl;
    int ec = cur[dl];                              // edge count (LDS broadcast)
    if (ec > BS - 1) ec = BS - 1;                  // reserve one slot for self
    int dcap = ec + 1;                             // slots incl. self
    int selfn = (node < NN) ? node : 0;
    int cbase = dl * BS;
    int cl0 = (l < ec) ? (int)cs[cbase + l]
                       : ((l == ec) ? selfn : 0);            // self folded in
    int cl1 = (l + 16 < ec) ? (int)cs[cbase + 16 + l]
                            : ((l + 16 == ec) ? selfn : 0);
    int cl2 = (l + 32 < ec) ? (int)cs[cbase + 32 + l]
                            : ((l + 32 == ec) ? selfn : 0);
    int maxd = dcap;
    maxd = max(maxd, __shfl_xor(maxd, 16));
    maxd = max(maxd, __shfl_xor(maxd, 32));        // wave-uniform trip bound
    float a0 = 0, a1 = 0, a2 = 0, a3 = 0, a4 = 0, a5 = 0, a6 = 0, a7 = 0;
    int nit = (maxd + 7) >> 3;                     // 8 slots per iteration
    for (int it = 0; it < nit; ++it) {
      int k0 = it << 3;
      int i0 = GSRC(k0);
      int i1 = GSRC(k0 + 1);
      int i2 = GSRC(k0 + 2);
      int i3 = GSRC(k0 + 3);
      int i4 = GSRC(k0 + 4);
      int i5 = GSRC(k0 + 5);
      int i6 = GSRC(k0 + 6);
      int i7 = GSRC(k0 + 7);
      uint4 v0 = xv[(unsigned)i0 * 16u + l];       // 8 rows in flight / lane
      uint4 v1 = xv[(unsigned)i1 * 16u + l];
      uint4 v2 = xv[(unsigned)i2 * 16u + l];
      uint4 v3 = xv[(unsigned)i3 * 16u + l];
      uint4 v4 = xv[(unsigned)i4 * 16u + l];
      uint4 v5 = xv[(unsigned)i5 * 16u + l];
      uint4 v6 = xv[(unsigned)i6 * 16u + l];
      uint4 v7 = xv[(unsigned)i7 * 16u + l];
      MSK(v0, k0) MSK(v1, k0 + 1) MSK(v2, k0 + 2) MSK(v3, k0 + 3)
      MSK(v4, k0 + 4) MSK(v5, k0 + 5) MSK(v6, k0 + 6) MSK(v7, k0 + 7)
      ACC8(v0) ACC8(v1) ACC8(v2) ACC8(v3)
      ACC8(v4) ACC8(v5) ACC8(v6) ACC8(v7)
    }
    uint4 o;
    o.x = (unsigned)f2bf(a0) | ((unsigned)f2bf(a1) << 16);
    o.y = (unsigned)f2bf(a2) | ((unsigned)f2bf(a3) << 16);
    o.z = (unsigned)f2bf(a4) | ((unsigned)f2bf(a5) << 16);
    o.w = (unsigned)f2bf(a6) | ((unsigned)f2bf(a7) << 16);
    tile[(dl * 16 + l) ^ (dl & 7)] = o;            // swizzled store (conflict-free)
  }
#undef GSRC
#undef MSK
#undef ACC8
  __syncthreads();                                 // phase 2 reads other waves' rows

  // ---------- phase 2: gemm1 — wave (row-half th, nf-half nh) of the 32-row tile
  {
    int th = w >> 1, nh = w & 1;
    int rbt = th * 16 + l;
    short8 a[4];
#pragma unroll
    for (int ks = 0; ks < 4; ++ks)
      a[ks] = *(const short8*)&tile[(rbt * 16 + ks * 4 + g) ^ (rbt & 7)];

    f32x4 acc[4];
#pragma unroll
    for (int nfl = 0; nfl < 4; ++nfl) { f32x4 z = {0.f, 0.f, 0.f, 0.f}; acc[nfl] = z; }

    const short8* B = (const short8*)W1p;
#pragma unroll
    for (int ks = 0; ks < 4; ++ks)
#pragma unroll
      for (int nfl = 0; nfl < 4; ++nfl) {
        int nf = nh * 4 + nfl;
        acc[nfl] = __builtin_amdgcn_mfma_f32_16x16x32_bf16(a[ks], B[(ks * 8 + nf) * 64 + lane],
                                                           acc[nfl], 0, 0, 0);
      }

#pragma unroll
    for (int nfl = 0; nfl < 4; ++nfl) {
      int colc = (nh * 4 + nfl) * 16 + l;
      float bias = b1[colc];
      float ps = 0.f, pq = 0.f;
#pragma unroll
      for (int r = 0; r < 4; ++r) {
        int row = b * 32 + th * 16 + g * 4 + r;
        float v = fmaxf(acc[nfl][r] + bias, 0.f);
        if (row < NN) {
          h1b[(int64_t)row * D + colc] = f2bf(v);
          ps += v; pq += v * v;
        }
      }
      ps += __shfl_xor(ps, 16); ps += __shfl_xor(ps, 32);
      pq += __shfl_xor(pq, 16); pq += __shfl_xor(pq, 32);
      if (g == 0) { atomicAdd(&redS[colc], ps); atomicAdd(&redQ[colc], pq); }
    }
  }
  __syncthreads();
  {
    int r = blockIdx.x & (NREP - 1);               // replicated stats: 16x less line contention
    if (t < D) {
      unsafeAtomicAdd(&stats[r * 256 + t], redS[t]);
      unsafeAtomicAdd(&stats[r * 256 + D + t], redQ[t]);
    }
  }
}

// ------------------------------------------------ k_head: BN-fold + collapsed linear head (fp32)
// logits = BN(h1) @ C + KB.  Grid matches k_fusedA (1563 x 32 nodes) so h1b
// rows are read on the same XCD's L2 that wrote them.
__global__ __launch_bounds__(256) void k_head(const unsigned short* __restrict__ h1b,
                                              const float* __restrict__ stats,
                                              const float* __restrict__ gamma,
                                              const float* __restrict__ beta,
                                              const float* __restrict__ Cf,
                                              const float* __restrict__ KBf,
                                              float* __restrict__ out) {
  __shared__ float sc_s[D], sh_s[D];
  __shared__ float2 c2_s[D];
  int t = threadIdx.x;
  if (t < D) {
    float s = 0.f, q = 0.f;
#pragma unroll
    for (int r = 0; r < NREP; ++r) {               // sum the 16 replicas
      s += stats[r * 256 + t];
      q += stats[r * 256 + D + t];
    }
    const float inv_n = 1.0f / (float)NN;
    float mean = s * inv_n;
    float var = q * inv_n - mean * mean;
    float sc = gamma[t] * rsqrtf(var + 1e-5f);
    sc_s[t] = sc;
    sh_s[t] = beta[t] - mean * sc;
    c2_s[t] = ((const float2*)Cf)[t];
  }
  __syncthreads();
  float2 kb = ((const float2*)KBf)[0];
  int l = t & 15;
  int k0 = l * 8;
#pragma unroll
  for (int rd = 0; rd < 2; ++rd) {
    int node = blockIdx.x * 32 + rd * 16 + (t >> 4);
    if (node < NN) {
      uint4 v = ((const uint4*)h1b)[(int64_t)node * 16 + l];
      float e0 = __uint_as_float(v.x << 16), e1 = __uint_as_float(v.x & 0xFFFF0000u);
      float e2 = __uint_as_float(v.y << 16), e3 = __uint_as_float(v.y & 0xFFFF0000u);
      float e4 = __uint_as_float(v.z << 16), e5 = __uint_as_float(v.z & 0xFFFF0000u);
      float e6 = __uint_as_float(v.w << 16), e7 = __uint_as_float(v.w & 0xFFFF0000u);
      float p0 = 0.f, p1 = 0.f;
#define HC(ej, jj) { float u_ = ej * sc_s[k0 + jj] + sh_s[k0 + jj];  \
                     float2 c_ = c2_s[k0 + jj];                      \
                     p0 += u_ * c_.x; p1 += u_ * c_.y; }
      HC(e0, 0) HC(e1, 1) HC(e2, 2) HC(e3, 3) HC(e4, 4) HC(e5, 5) HC(e6, 6) HC(e7, 7)
#undef HC
      p0 += __shfl_xor(p0, 1); p0 += __shfl_xor(p0, 2);
      p0 += __shfl_xor(p0, 4); p0 += __shfl_xor(p0, 8);
      p1 += __shfl_xor(p1, 1); p1 += __shfl_xor(p1, 2);
      p1 += __shfl_xor(p1, 4); p1 += __shfl_xor(p1, 8);
      if (l == 0) ((float2*)out)[node] = make_float2(p0 + kb.x, p1 + kb.y);
    }
  }
}

// ------------------------------------------------ launcher
extern "C" void kernel_launch(void* const* d_in, const int* in_sizes, int n_in,
                              void* d_out, int out_size, void* d_ws, size_t ws_size,
                              hipStream_t stream) {
  const float* x     = (const float*)d_in[0];
  const int*   ei    = (const int*)d_in[1];
  const float* W1    = (const float*)d_in[2];
  const float* b1    = (const float*)d_in[3];
  const float* gamma = (const float*)d_in[4];
  const float* beta  = (const float*)d_in[5];
  const float* W2    = (const float*)d_in[6];
  const float* b2    = (const float*)d_in[7];
  const float* Wl    = (const float*)d_in[8];
  const float* bl    = (const float*)d_in[9];
  float* out = (float*)d_out;

  // workspace layout (~30 MB)
  unsigned short* xb  = (unsigned short*)d_ws;            // NN*D
  unsigned short* h1b = xb + (int64_t)NN * D;             // NN*D
  unsigned short* W1p = h1b + (int64_t)NN * D;            // 16384
  float* Cf     = (float*)(W1p + 16384);                  // 256 floats (C = W2@Wl as float2[128])
  float* KBf    = Cf + 256;                               // 4 floats (2 used)
  float* stats  = KBf + 4;                                // NREP*256 floats (replicated S|Q)
  int* gcnt     = (int*)(stats + NREP * 256);             // NB2 ints (contiguous: one memset)
  unsigned* pairs = (unsigned*)(gcnt + NB2);              // NB2*PCAP2 (~4 MB)

  hipMemsetAsync(stats, 0, (NREP * 256 + NB2) * sizeof(float), stream);  // stats + gcnt
  k_prep<<<FA + WB1 + 1 + XB4, 256, 0, stream>>>(x, W1, W2, Wl, b2, bl, ei,
                                                 xb, W1p, Cf, KBf, gcnt, pairs);
  k_fusedA<<<NB2, 256, 0, stream>>>(xb, gcnt, pairs, W1p, b1, h1b, stats);
  k_head<<<NB2, 256, 0, stream>>>(h1b, stats, gamma, beta, Cf, KBf, out);
}